// Round 4
// baseline (1099.796 us; speedup 1.0000x reference)
//
#include <hip/hip_runtime.h>

#define N_WALK 4096
#define N_EL   32
#define DIM    64
#define HPAD   68   // f32 row stride: 68%32=4 banks -> max 2-way conflict (free)
#define NLAY   3
#define KDET   16
#define NPAIR  496
#define TWO_PI_D 6.283185307179586476925286766559

// accurate f64 silu for quantization-faithful activation
__device__ __forceinline__ double silu_d(double x) {
  return x / (1.0 + exp(-x));
}
__device__ __forceinline__ float silu_f(float x) {
  return x / (1.0f + expf(-x));
}

__global__ __launch_bounds__(256) void wf_kernel(
    const float* __restrict__ r_el,
    const float* __restrict__ cell,
    const float* __restrict__ W_e,  const float* __restrict__ b_e,
    const float* __restrict__ W_pw, const float* __restrict__ b_pw,
    const float* __restrict__ W1,   const float* __restrict__ b1,
    const float* __restrict__ W2,   const float* __restrict__ b2,
    const float* __restrict__ ln_w, const float* __restrict__ ln_b,
    const float* __restrict__ W_up, const float* __restrict__ b_up,
    const float* __restrict__ W_dn, const float* __restrict__ b_dn,
    const float* __restrict__ det_w,
    const float* __restrict__ Wj1,  const float* __restrict__ bj1,
    const float* __restrict__ Wj2,  const float* __restrict__ bj2,
    const float* __restrict__ Wj3,  const float* __restrict__ bj3,
    const float* __restrict__ jscale,
    float* __restrict__ out)
{
  __shared__ float s_linv[9];          // f32 inverse (mirrors np's f32 L_inv tensor)
  __shared__ float s_cl[9];            // f32 cell
  __shared__ float s_r[N_EL][3];       // wrapped positions, f32 (np tensor)
  __shared__ float s_pw[N_EL][6];      // plane-wave features, f32 (np tensor)
  __shared__ float s_h[N_EL][HPAD];    // h, f32 (np tensor after every layer)
  __shared__ float s_y[N_EL][HPAD];    // silu output, f32 (np tensor)
  __shared__ float s_hm[DIM];          // mean-field, f32 (np tensor)
  __shared__ double s_lu[2][KDET];
  __shared__ float  s_su[2][KDET];
  __shared__ float  s_red[4];

  const int t = threadIdx.x;
  const int w = blockIdx.x;

  // ---- cell inverse: compute in f64, round to f32 (≈ np's f32 inv ± 1ulp) ----
  if (t == 0) {
    double m00=cell[0], m01=cell[1], m02=cell[2];
    double m10=cell[3], m11=cell[4], m12=cell[5];
    double m20=cell[6], m21=cell[7], m22=cell[8];
    double c00 = m11*m22 - m12*m21;
    double c10 = m12*m20 - m10*m22;
    double c20 = m10*m21 - m11*m20;
    double det = m00*c00 + m01*c10 + m02*c20;
    double id = 1.0/det;
    s_linv[0]=(float)(c00*id); s_linv[1]=(float)((m02*m21-m01*m22)*id); s_linv[2]=(float)((m01*m12-m02*m11)*id);
    s_linv[3]=(float)(c10*id); s_linv[4]=(float)((m00*m22-m02*m20)*id); s_linv[5]=(float)((m02*m10-m00*m12)*id);
    s_linv[6]=(float)(c20*id); s_linv[7]=(float)((m01*m20-m00*m21)*id); s_linv[8]=(float)((m00*m11-m01*m10)*id);
    #pragma unroll
    for (int i=0;i<9;i++) s_cl[i]=cell[i];
  }
  __syncthreads();

  // ---- stage 1: wrap + plane waves. f64 dots of f32 operands, f32 rounds at
  //      every np tensor boundary; floor() input quantized to f32. ----
  if (t < N_EL) {
    const float* rp = r_el + ((size_t)w * N_EL + t) * 3;
    const float rx = rp[0], ry = rp[1], rz = rp[2];
    float s0 = (float)((double)s_linv[0]*rx + (double)s_linv[1]*ry + (double)s_linv[2]*rz);
    float s1 = (float)((double)s_linv[3]*rx + (double)s_linv[4]*ry + (double)s_linv[5]*rz);
    float s2 = (float)((double)s_linv[6]*rx + (double)s_linv[7]*ry + (double)s_linv[8]*rz);
    s0 -= floorf(s0); s1 -= floorf(s1); s2 -= floorf(s2);
    const float wx = (float)((double)s0*s_cl[0] + (double)s1*s_cl[3] + (double)s2*s_cl[6]);
    const float wy = (float)((double)s0*s_cl[1] + (double)s1*s_cl[4] + (double)s2*s_cl[7]);
    const float wz = (float)((double)s0*s_cl[2] + (double)s1*s_cl[5] + (double)s2*s_cl[8]);
    s_r[t][0]=wx; s_r[t][1]=wy; s_r[t][2]=wz;
    const float u0 = (float)((double)s_linv[0]*wx + (double)s_linv[1]*wy + (double)s_linv[2]*wz);
    const float u1 = (float)((double)s_linv[3]*wx + (double)s_linv[4]*wy + (double)s_linv[5]*wz);
    const float u2 = (float)((double)s_linv[6]*wx + (double)s_linv[7]*wy + (double)s_linv[8]*wz);
    double sn, cs;
    sincos(TWO_PI_D*(double)u0, &sn, &cs); s_pw[t][0]=(float)sn; s_pw[t][3]=(float)cs;
    sincos(TWO_PI_D*(double)u1, &sn, &cs); s_pw[t][1]=(float)sn; s_pw[t][4]=(float)cs;
    sincos(TWO_PI_D*(double)u2, &sn, &cs); s_pw[t][2]=(float)sn; s_pw[t][5]=(float)cs;
  }
  __syncthreads();

  // ---- stage 2: h0 = r@W_e + b_e + pw@W_pw + b_pw (f64 acc -> f32 store) ----
  {
    const int e = t >> 3, db = (t & 7) * 8;
    const double rx=s_r[e][0], ry=s_r[e][1], rz=s_r[e][2];
    const double p0=s_pw[e][0],p1=s_pw[e][1],p2=s_pw[e][2];
    const double p3=s_pw[e][3],p4=s_pw[e][4],p5=s_pw[e][5];
    #pragma unroll
    for (int u=0;u<8;u++) {
      const int d = db+u;
      double acc = (double)b_e[d] + (double)b_pw[d];
      acc = fma(rx, (double)W_e[0*DIM+d], acc);
      acc = fma(ry, (double)W_e[1*DIM+d], acc);
      acc = fma(rz, (double)W_e[2*DIM+d], acc);
      acc = fma(p0, (double)W_pw[0*DIM+d], acc);
      acc = fma(p1, (double)W_pw[1*DIM+d], acc);
      acc = fma(p2, (double)W_pw[2*DIM+d], acc);
      acc = fma(p3, (double)W_pw[3*DIM+d], acc);
      acc = fma(p4, (double)W_pw[4*DIM+d], acc);
      acc = fma(p5, (double)W_pw[5*DIM+d], acc);
      s_h[e][d] = (float)acc;
    }
  }
  __syncthreads();

  // ---- stage 3: interaction layers. f64 accumulation, f32 at np tensor
  //      boundaries (hm, x=h*hm, pre1, y, delta, h_new). ----
  for (int L = 0; L < NLAY; ++L) {
    const float* __restrict__ w1 = W1 + (size_t)L*192*DIM;
    const float* __restrict__ w2 = W2 + (size_t)L*DIM*DIM;

    if (t < DIM) {
      double s = 0.0;
      #pragma unroll 8
      for (int e=0;e<N_EL;e++) s += (double)s_h[e][t];
      s_hm[t] = (float)(s * (1.0/N_EL));
    }
    __syncthreads();

    // y = silu([h, hm, h*hm] @ W1 + b1)
    {
      const int e = t >> 3, jb = (t & 7) * 8;
      double acc[8];
      #pragma unroll
      for (int u=0;u<8;u++) acc[u] = (double)b1[L*DIM + jb + u];
      for (int i=0;i<DIM;i++) {
        const float xhf = s_h[e][i];
        const float xmf = s_hm[i];
        const float xcf = xhf * xmf;          // f32 tensor h*hm (np materializes it)
        const double xh = (double)xhf, xm = (double)xmf, xc = (double)xcf;
        const float* ra = w1 + i*DIM + jb;
        const float* rb = ra + 64*DIM;
        const float* rc = ra + 128*DIM;
        const float4 a0 = *(const float4*)ra, a1 = *(const float4*)(ra+4);
        const float4 b0 = *(const float4*)rb, b1v = *(const float4*)(rb+4);
        const float4 c0 = *(const float4*)rc, c1 = *(const float4*)(rc+4);
        acc[0]=fma(xh,(double)a0.x,acc[0]); acc[1]=fma(xh,(double)a0.y,acc[1]);
        acc[2]=fma(xh,(double)a0.z,acc[2]); acc[3]=fma(xh,(double)a0.w,acc[3]);
        acc[4]=fma(xh,(double)a1.x,acc[4]); acc[5]=fma(xh,(double)a1.y,acc[5]);
        acc[6]=fma(xh,(double)a1.z,acc[6]); acc[7]=fma(xh,(double)a1.w,acc[7]);
        acc[0]=fma(xm,(double)b0.x,acc[0]); acc[1]=fma(xm,(double)b0.y,acc[1]);
        acc[2]=fma(xm,(double)b0.z,acc[2]); acc[3]=fma(xm,(double)b0.w,acc[3]);
        acc[4]=fma(xm,(double)b1v.x,acc[4]); acc[5]=fma(xm,(double)b1v.y,acc[5]);
        acc[6]=fma(xm,(double)b1v.z,acc[6]); acc[7]=fma(xm,(double)b1v.w,acc[7]);
        acc[0]=fma(xc,(double)c0.x,acc[0]); acc[1]=fma(xc,(double)c0.y,acc[1]);
        acc[2]=fma(xc,(double)c0.z,acc[2]); acc[3]=fma(xc,(double)c0.w,acc[3]);
        acc[4]=fma(xc,(double)c1.x,acc[4]); acc[5]=fma(xc,(double)c1.y,acc[5]);
        acc[6]=fma(xc,(double)c1.z,acc[6]); acc[7]=fma(xc,(double)c1.w,acc[7]);
      }
      #pragma unroll
      for (int u=0;u<8;u++) {
        const float pre = (float)acc[u];                 // np's f32 pre-activation
        s_y[e][jb+u] = (float)silu_d((double)pre);       // np's f32 silu output
      }
    }
    __syncthreads();

    // delta = y @ W2 + b2 ; h = LN(h + delta)
    {
      const int e = t >> 3, db = (t & 7) * 8;
      double acc[8];
      #pragma unroll
      for (int u=0;u<8;u++) acc[u] = (double)b2[L*DIM + db + u];
      for (int j=0;j<DIM;j++) {
        const double yv = (double)s_y[e][j];
        const float* rr = w2 + j*DIM + db;
        const float4 a0 = *(const float4*)rr, a1 = *(const float4*)(rr+4);
        acc[0]=fma(yv,(double)a0.x,acc[0]); acc[1]=fma(yv,(double)a0.y,acc[1]);
        acc[2]=fma(yv,(double)a0.z,acc[2]); acc[3]=fma(yv,(double)a0.w,acc[3]);
        acc[4]=fma(yv,(double)a1.x,acc[4]); acc[5]=fma(yv,(double)a1.y,acc[5]);
        acc[6]=fma(yv,(double)a1.z,acc[6]); acc[7]=fma(yv,(double)a1.w,acc[7]);
      }
      float v[8];
      double ps=0.0, pss=0.0;
      #pragma unroll
      for (int u=0;u<8;u++) {
        const float delta = (float)acc[u];      // np's f32 delta tensor
        v[u] = s_h[e][db+u] + delta;            // f32 add (np's h+delta tensor)
        ps += (double)v[u]; pss += (double)v[u]*(double)v[u];
      }
      #pragma unroll
      for (int off=4; off>=1; off>>=1) {
        ps  += __shfl_xor(ps,  off, 8);
        pss += __shfl_xor(pss, off, 8);
      }
      const double mu = ps * (1.0/DIM);
      double var = pss * (1.0/DIM) - mu*mu;
      var = fmax(var, 0.0);
      const double rstd = 1.0 / sqrt(var + 1e-5);
      #pragma unroll
      for (int u=0;u<8;u++) {
        const int d = db+u;
        s_h[e][d] = (float)(((double)v[u]-mu)*rstd*(double)ln_w[L*DIM+d] + (double)ln_b[L*DIM+d]);
      }
    }
    __syncthreads();
  }

  // ---- stage 4: Jastrow (f32 like np; sij quantized to f32 BEFORE rint) ----
  float jpart = 0.f;
  for (int p = t; p < NPAIR; p += 256) {
    int i = 0, rem = p;
    while (rem >= (N_EL-1) - i) { rem -= (N_EL-1) - i; ++i; }
    const int j = i + 1 + rem;
    const float dx = s_r[i][0]-s_r[j][0];
    const float dy = s_r[i][1]-s_r[j][1];
    const float dz = s_r[i][2]-s_r[j][2];
    float q0 = (float)((double)s_linv[0]*dx + (double)s_linv[1]*dy + (double)s_linv[2]*dz);
    float q1 = (float)((double)s_linv[3]*dx + (double)s_linv[4]*dy + (double)s_linv[5]*dz);
    float q2 = (float)((double)s_linv[6]*dx + (double)s_linv[7]*dy + (double)s_linv[8]*dz);
    q0 -= rintf(q0); q1 -= rintf(q1); q2 -= rintf(q2);
    const float vx = (float)((double)q0*s_cl[0] + (double)q1*s_cl[3] + (double)q2*s_cl[6]);
    const float vy = (float)((double)q0*s_cl[1] + (double)q1*s_cl[4] + (double)q2*s_cl[7]);
    const float vz = (float)((double)q0*s_cl[2] + (double)q1*s_cl[5] + (double)q2*s_cl[8]);
    const float rij = sqrtf(vx*vx + vy*vy + vz*vz);
    float h1[32];
    #pragma unroll
    for (int m=0;m<32;m++) h1[m] = silu_f(fmaf(rij, Wj1[m], bj1[m]));
    float o = bj3[0];
    for (int n=0;n<32;n++) {
      float a2 = bj2[n];
      #pragma unroll
      for (int m=0;m<32;m++) a2 = fmaf(h1[m], Wj2[m*32+n], a2);
      o = fmaf(silu_f(a2), Wj3[n], o);
    }
    jpart += o;
  }
  #pragma unroll
  for (int off=32; off>=1; off>>=1) jpart += __shfl_xor(jpart, off, 64);
  if ((t & 63) == 0) s_red[t >> 6] = jpart;
  __syncthreads();

  // ---- stage 5+6: row-owned orbitals (f64 acc -> f32 round, = np's f32 orb
  //      tensor) then f64 LU with PHYSICAL row swaps (LAPACK structure). ----
  // lane layout: det g = t>>4, row r = t&15. Lane holds row r of phi[g]:
  //   a[j] = orb[sp*16+r][g*16+j]
  {
    const int g = t >> 4;
    const int r = t & 15;
    const int c0 = g * 16;
    #pragma unroll 1
    for (int sp=0; sp<2; ++sp) {
      const float* __restrict__ Wo = sp ? W_dn : W_up;
      const float* __restrict__ bo = sp ? b_dn : b_up;
      const int hrow = sp*16 + r;
      double acc[16];
      #pragma unroll
      for (int j=0;j<16;j++) acc[j] = (double)bo[c0+j];
      for (int d=0; d<DIM; d++) {
        const double hv = (double)s_h[hrow][d];
        const float* wr = Wo + (size_t)d*256 + c0;
        const float4 w0 = *(const float4*)(wr);
        const float4 w1v = *(const float4*)(wr+4);
        const float4 w2v = *(const float4*)(wr+8);
        const float4 w3v = *(const float4*)(wr+12);
        acc[0] =fma(hv,(double)w0.x, acc[0]);  acc[1] =fma(hv,(double)w0.y, acc[1]);
        acc[2] =fma(hv,(double)w0.z, acc[2]);  acc[3] =fma(hv,(double)w0.w, acc[3]);
        acc[4] =fma(hv,(double)w1v.x,acc[4]);  acc[5] =fma(hv,(double)w1v.y,acc[5]);
        acc[6] =fma(hv,(double)w1v.z,acc[6]);  acc[7] =fma(hv,(double)w1v.w,acc[7]);
        acc[8] =fma(hv,(double)w2v.x,acc[8]);  acc[9] =fma(hv,(double)w2v.y,acc[9]);
        acc[10]=fma(hv,(double)w2v.z,acc[10]); acc[11]=fma(hv,(double)w2v.w,acc[11]);
        acc[12]=fma(hv,(double)w3v.x,acc[12]); acc[13]=fma(hv,(double)w3v.y,acc[13]);
        acc[14]=fma(hv,(double)w3v.z,acc[14]); acc[15]=fma(hv,(double)w3v.w,acc[15]);
      }
      double a[16];
      #pragma unroll
      for (int j=0;j<16;j++) a[j] = (double)(float)acc[j];   // f32 round = np orb

      // --- LU, partial pivoting with physical row swaps ---
      double prod = 1.0;
      int par = 0;
      #pragma unroll
      for (int k=0;k<16;k++) {
        // argmax |a[k]| over rows r>=k (uniform result in all lanes)
        double bv = (r >= k) ? fabs(a[k]) : -1.0;
        int bi = r;
        #pragma unroll
        for (int off=8; off>=1; off>>=1) {
          const double ov = __shfl_xor(bv, off, 16);
          const int    oi = __shfl_xor(bi, off, 16);
          if (ov > bv || (ov == bv && oi < bi)) { bv = ov; bi = oi; }
        }
        const int p = bi;
        par += (p != k) ? 1 : 0;
        // physically swap rows k <-> p (columns j>=k suffice)
        #pragma unroll
        for (int j=k;j<16;j++) {
          const double rk = __shfl(a[j], k, 16);
          const double rp = __shfl(a[j], p, 16);
          a[j] = (r == k) ? rp : ((r == p) ? rk : a[j]);
        }
        const double piv = __shfl(a[k], k, 16);   // uniform
        prod *= piv;
        const double f = (r > k && piv != 0.0) ? a[k]/piv : 0.0;
        #pragma unroll
        for (int j=k+1;j<16;j++) {
          const double rkj = __shfl(a[j], k, 16);
          a[j] = fma(-f, rkj, a[j]);
        }
      }
      if (r == 0) {
        s_lu[sp][g] = log(fabs(prod));
        const int neg = (prod < 0.0) ? 1 : 0;
        s_su[sp][g] = ((par + neg) & 1) ? -1.f : 1.f;
      }
    }
  }
  __syncthreads();

  // ---- stage 7: signed logsumexp combine (f64) ----
  if (t == 0) {
    double ww[KDET]; double mw = -1e300;
    #pragma unroll
    for (int k=0;k<KDET;k++) { ww[k] = (double)det_w[k]; mw = fmax(mw, ww[k]); }
    double sum = 0.0;
    #pragma unroll
    for (int k=0;k<KDET;k++) { ww[k] = exp(ww[k]-mw); sum += ww[k]; }
    const double inv_sum = 1.0/sum;
    double m = -1e300; double logs[KDET]; double sg[KDET];
    #pragma unroll
    for (int k=0;k<KDET;k++) {
      logs[k] = s_lu[0][k] + s_lu[1][k] + log(ww[k]*inv_sum + 1e-10);
      sg[k] = (double)(s_su[0][k] * s_su[1][k]);
      m = fmax(m, logs[k]);
    }
    double ssum = 0.0;
    #pragma unroll
    for (int k=0;k<KDET;k++) ssum += sg[k] * exp(logs[k]-m);
    const double jas = (double)jscale[0] * (double)(s_red[0]+s_red[1]+s_red[2]+s_red[3]);
    out[w] = (float)(jas + m + log(fabs(ssum) + 1e-30));
    out[N_WALK + w] = (ssum > 0.0) ? 1.f : ((ssum < 0.0) ? -1.f : 0.f);
  }
}

extern "C" void kernel_launch(void* const* d_in, const int* in_sizes, int n_in,
                              void* d_out, int out_size, void* d_ws, size_t ws_size,
                              hipStream_t stream) {
  const float* r_el  = (const float*)d_in[0];
  const float* cell  = (const float*)d_in[1];
  // d_in[2] = twist (unused by the reference)
  const float* W_e   = (const float*)d_in[3];
  const float* b_e   = (const float*)d_in[4];
  const float* W_pw  = (const float*)d_in[5];
  const float* b_pw  = (const float*)d_in[6];
  const float* W1    = (const float*)d_in[7];
  const float* b1    = (const float*)d_in[8];
  const float* W2    = (const float*)d_in[9];
  const float* b2    = (const float*)d_in[10];
  const float* ln_w  = (const float*)d_in[11];
  const float* ln_b  = (const float*)d_in[12];
  const float* W_up  = (const float*)d_in[13];
  const float* b_up  = (const float*)d_in[14];
  const float* W_dn  = (const float*)d_in[15];
  const float* b_dn  = (const float*)d_in[16];
  const float* det_w = (const float*)d_in[17];
  const float* Wj1   = (const float*)d_in[18];
  const float* bj1   = (const float*)d_in[19];
  const float* Wj2   = (const float*)d_in[20];
  const float* bj2   = (const float*)d_in[21];
  const float* Wj3   = (const float*)d_in[22];
  const float* bj3   = (const float*)d_in[23];
  const float* jsc   = (const float*)d_in[24];

  wf_kernel<<<N_WALK, 256, 0, stream>>>(
      r_el, cell, W_e, b_e, W_pw, b_pw, W1, b1, W2, b2, ln_w, ln_b,
      W_up, b_up, W_dn, b_dn, det_w, Wj1, bj1, Wj2, bj2, Wj3, bj3, jsc,
      (float*)d_out);
}

// Round 6
// 885.113 us; speedup vs baseline: 1.2425x; 1.2425x over previous
//
#include <hip/hip_runtime.h>

#define N_WALK 4096
#define N_EL   32
#define DIM    64
#define HPAD   68   // f32 row stride: 68%32=4 banks -> max 2-way conflict (free)
#define NLAY   3
#define KDET   16
#define NPAIR  496
#define TWO_PI_D 6.283185307179586476925286766559

using f64x4 = __attribute__((ext_vector_type(4))) double;

__device__ __forceinline__ double silu_d(double x) { return x / (1.0 + exp(-x)); }
__device__ __forceinline__ float  silu_f(float x)  { return x / (1.0f + expf(-x)); }

#define MFMA64(A, B, C) __builtin_amdgcn_mfma_f64_16x16x4f64((A), (B), (C), 0, 0, 0)

__global__ __launch_bounds__(256) void wf_kernel(
    const float* __restrict__ r_el,
    const float* __restrict__ cell,
    const float* __restrict__ W_e,  const float* __restrict__ b_e,
    const float* __restrict__ W_pw, const float* __restrict__ b_pw,
    const float* __restrict__ W1,   const float* __restrict__ b1,
    const float* __restrict__ W2,   const float* __restrict__ b2,
    const float* __restrict__ ln_w, const float* __restrict__ ln_b,
    const float* __restrict__ W_up, const float* __restrict__ b_up,
    const float* __restrict__ W_dn, const float* __restrict__ b_dn,
    const float* __restrict__ det_w,
    const float* __restrict__ Wj1,  const float* __restrict__ bj1,
    const float* __restrict__ Wj2,  const float* __restrict__ bj2,
    const float* __restrict__ Wj3,  const float* __restrict__ bj3,
    const float* __restrict__ jscale,
    float* __restrict__ out)
{
  __shared__ float s_linv[9];
  __shared__ float s_cl[9];
  __shared__ float s_r[N_EL][3];
  __shared__ float s_pw[N_EL][6];
  __shared__ float s_h[N_EL][HPAD];
  __shared__ float s_y[N_EL][HPAD];   // y, then v=h+delta
  __shared__ float s_hm[DIM];
  __shared__ float s_orb[2][16][256]; // phi (f32-rounded, np's orb tensor)
  __shared__ double s_lu[2][KDET];
  __shared__ float  s_su[2][KDET];
  __shared__ float  s_red[4];

  const int t = threadIdx.x;
  const int w = blockIdx.x;
  const int wv = t >> 6;         // wave id 0..3
  const int l  = t & 63;
  const int lr = l & 15;         // row/col fragment index
  const int lq = l >> 4;         // k fragment index

  // ---- cell inverse: f64 compute, f32 round ----
  if (t == 0) {
    double m00=cell[0], m01=cell[1], m02=cell[2];
    double m10=cell[3], m11=cell[4], m12=cell[5];
    double m20=cell[6], m21=cell[7], m22=cell[8];
    double c00 = m11*m22 - m12*m21;
    double c10 = m12*m20 - m10*m22;
    double c20 = m10*m21 - m11*m20;
    double det = m00*c00 + m01*c10 + m02*c20;
    double id = 1.0/det;
    s_linv[0]=(float)(c00*id); s_linv[1]=(float)((m02*m21-m01*m22)*id); s_linv[2]=(float)((m01*m12-m02*m11)*id);
    s_linv[3]=(float)(c10*id); s_linv[4]=(float)((m00*m22-m02*m20)*id); s_linv[5]=(float)((m02*m10-m00*m12)*id);
    s_linv[6]=(float)(c20*id); s_linv[7]=(float)((m01*m20-m00*m21)*id); s_linv[8]=(float)((m00*m11-m01*m10)*id);
    #pragma unroll
    for (int i=0;i<9;i++) s_cl[i]=cell[i];
  }
  __syncthreads();

  // ---- stage 1: wrap + plane waves (f64 dots, f32 tensor boundaries) ----
  if (t < N_EL) {
    const float* rp = r_el + ((size_t)w * N_EL + t) * 3;
    const float rx = rp[0], ry = rp[1], rz = rp[2];
    float s0 = (float)((double)s_linv[0]*rx + (double)s_linv[1]*ry + (double)s_linv[2]*rz);
    float s1 = (float)((double)s_linv[3]*rx + (double)s_linv[4]*ry + (double)s_linv[5]*rz);
    float s2 = (float)((double)s_linv[6]*rx + (double)s_linv[7]*ry + (double)s_linv[8]*rz);
    s0 -= floorf(s0); s1 -= floorf(s1); s2 -= floorf(s2);
    const float wx = (float)((double)s0*s_cl[0] + (double)s1*s_cl[3] + (double)s2*s_cl[6]);
    const float wy = (float)((double)s0*s_cl[1] + (double)s1*s_cl[4] + (double)s2*s_cl[7]);
    const float wz = (float)((double)s0*s_cl[2] + (double)s1*s_cl[5] + (double)s2*s_cl[8]);
    s_r[t][0]=wx; s_r[t][1]=wy; s_r[t][2]=wz;
    const float u0 = (float)((double)s_linv[0]*wx + (double)s_linv[1]*wy + (double)s_linv[2]*wz);
    const float u1 = (float)((double)s_linv[3]*wx + (double)s_linv[4]*wy + (double)s_linv[5]*wz);
    const float u2 = (float)((double)s_linv[6]*wx + (double)s_linv[7]*wy + (double)s_linv[8]*wz);
    double sn, cs;
    sincos(TWO_PI_D*(double)u0, &sn, &cs); s_pw[t][0]=(float)sn; s_pw[t][3]=(float)cs;
    sincos(TWO_PI_D*(double)u1, &sn, &cs); s_pw[t][1]=(float)sn; s_pw[t][4]=(float)cs;
    sincos(TWO_PI_D*(double)u2, &sn, &cs); s_pw[t][2]=(float)sn; s_pw[t][5]=(float)cs;
  }
  __syncthreads();

  // ---- stage 2: h0 (f64 acc -> f32 store) ----
  {
    const int e = t >> 3, db = (t & 7) * 8;
    const double rx=s_r[e][0], ry=s_r[e][1], rz=s_r[e][2];
    const double p0=s_pw[e][0],p1=s_pw[e][1],p2=s_pw[e][2];
    const double p3=s_pw[e][3],p4=s_pw[e][4],p5=s_pw[e][5];
    #pragma unroll
    for (int u=0;u<8;u++) {
      const int d = db+u;
      double acc = (double)b_e[d] + (double)b_pw[d];
      acc = fma(rx, (double)W_e[0*DIM+d], acc);
      acc = fma(ry, (double)W_e[1*DIM+d], acc);
      acc = fma(rz, (double)W_e[2*DIM+d], acc);
      acc = fma(p0, (double)W_pw[0*DIM+d], acc);
      acc = fma(p1, (double)W_pw[1*DIM+d], acc);
      acc = fma(p2, (double)W_pw[2*DIM+d], acc);
      acc = fma(p3, (double)W_pw[3*DIM+d], acc);
      acc = fma(p4, (double)W_pw[4*DIM+d], acc);
      acc = fma(p5, (double)W_pw[5*DIM+d], acc);
      s_h[e][d] = (float)acc;
    }
  }
  __syncthreads();

  // ---- stage 3: interaction layers via f64 MFMA ----
  // wave tile map: m = wv&1 (M-tile), nb = (wv>>1)*2 (first of 2 N-tiles)
  for (int L = 0; L < NLAY; ++L) {
    const float* __restrict__ w1p = W1 + (size_t)L*192*DIM;
    const float* __restrict__ w2p = W2 + (size_t)L*DIM*DIM;

    if (t < DIM) {
      double s = 0.0;
      #pragma unroll 8
      for (int e=0;e<N_EL;e++) s += (double)s_h[e][t];
      s_hm[t] = (float)(s * (1.0/N_EL));
    }
    __syncthreads();

    const int m  = wv & 1;
    const int nb = (wv >> 1) * 2;
    const int ea = m*16 + lr;        // A-fragment row (electron)
    const int c0 = nb*16 + lr;       // D/B column of tile 0 (tile 1 = c0+16)
    const int er = m*16 + lq*4;      // D row base

    // --- y = silu([h, hm, h*hm] @ W1 + b1) ---
    {
      f64x4 a0 = {0.0,0.0,0.0,0.0}, a1 = {0.0,0.0,0.0,0.0};
      #pragma unroll
      for (int kk=0;kk<16;kk++) {              // K seg 0: x = h
        const int km = kk*4 + lq;
        const double af = (double)s_h[ea][km];
        const double q0 = (double)w1p[km*DIM + c0];
        const double q1 = (double)w1p[km*DIM + c0 + 16];
        a0 = MFMA64(af, q0, a0);
        a1 = MFMA64(af, q1, a1);
      }
      #pragma unroll
      for (int kk=0;kk<16;kk++) {              // K seg 1: x = hm
        const int km = kk*4 + lq;
        const double af = (double)s_hm[km];
        const double q0 = (double)w1p[(64+km)*DIM + c0];
        const double q1 = (double)w1p[(64+km)*DIM + c0 + 16];
        a0 = MFMA64(af, q0, a0);
        a1 = MFMA64(af, q1, a1);
      }
      #pragma unroll
      for (int kk=0;kk<16;kk++) {              // K seg 2: x = h*hm (f32 product)
        const int km = kk*4 + lq;
        const double af = (double)(s_h[ea][km] * s_hm[km]);
        const double q0 = (double)w1p[(128+km)*DIM + c0];
        const double q1 = (double)w1p[(128+km)*DIM + c0 + 16];
        a0 = MFMA64(af, q0, a0);
        a1 = MFMA64(af, q1, a1);
      }
      #pragma unroll
      for (int v=0;v<4;v++) {
        const float p0 = (float)(a0[v] + (double)b1[L*DIM + c0]);      // np pre-act
        const float p1 = (float)(a1[v] + (double)b1[L*DIM + c0 + 16]);
        s_y[er+v][c0]      = (float)silu_d((double)p0);
        s_y[er+v][c0 + 16] = (float)silu_d((double)p1);
      }
    }
    __syncthreads();

    // --- delta = y @ W2 + b2 ; v = h + delta ---
    {
      f64x4 a0 = {0.0,0.0,0.0,0.0}, a1 = {0.0,0.0,0.0,0.0};
      #pragma unroll
      for (int kk=0;kk<16;kk++) {
        const int km = kk*4 + lq;
        const double af = (double)s_y[ea][km];
        const double q0 = (double)w2p[km*DIM + c0];
        const double q1 = (double)w2p[km*DIM + c0 + 16];
        a0 = MFMA64(af, q0, a0);
        a1 = MFMA64(af, q1, a1);
      }
      __syncthreads();   // all waves done READING s_y; now overwrite with v
      #pragma unroll
      for (int v=0;v<4;v++) {
        const float d0 = (float)(a0[v] + (double)b2[L*DIM + c0]);      // np delta
        const float d1 = (float)(a1[v] + (double)b2[L*DIM + c0 + 16]);
        s_y[er+v][c0]      = s_h[er+v][c0]      + d0;                  // np h+delta
        s_y[er+v][c0 + 16] = s_h[er+v][c0 + 16] + d1;
      }
    }
    __syncthreads();

    // --- LayerNorm: stats f64, tensors f32 (reads s_y, writes s_h) ---
    {
      const int e = t >> 3, db = (t & 7) * 8;
      float v[8];
      double ps=0.0, pss=0.0;
      #pragma unroll
      for (int u=0;u<8;u++) {
        v[u] = s_y[e][db+u];
        ps += (double)v[u]; pss += (double)v[u]*(double)v[u];
      }
      #pragma unroll
      for (int off=4; off>=1; off>>=1) {
        ps  += __shfl_xor(ps,  off, 8);
        pss += __shfl_xor(pss, off, 8);
      }
      const double mu = ps * (1.0/DIM);
      double var = pss * (1.0/DIM) - mu*mu;
      var = fmax(var, 0.0);
      const double rstd = 1.0 / sqrt(var + 1e-5);
      #pragma unroll
      for (int u=0;u<8;u++) {
        const int d = db+u;
        s_h[e][d] = (float)(((double)v[u]-mu)*rstd*(double)ln_w[L*DIM+d] + (double)ln_b[L*DIM+d]);
      }
    }
    __syncthreads();
  }

  // ---- stage 4: Jastrow (R4 verbatim) ----
  float jpart = 0.f;
  for (int p = t; p < NPAIR; p += 256) {
    int i = 0, rem = p;
    while (rem >= (N_EL-1) - i) { rem -= (N_EL-1) - i; ++i; }
    const int j = i + 1 + rem;
    const float dx = s_r[i][0]-s_r[j][0];
    const float dy = s_r[i][1]-s_r[j][1];
    const float dz = s_r[i][2]-s_r[j][2];
    float q0 = (float)((double)s_linv[0]*dx + (double)s_linv[1]*dy + (double)s_linv[2]*dz);
    float q1 = (float)((double)s_linv[3]*dx + (double)s_linv[4]*dy + (double)s_linv[5]*dz);
    float q2 = (float)((double)s_linv[6]*dx + (double)s_linv[7]*dy + (double)s_linv[8]*dz);
    q0 -= rintf(q0); q1 -= rintf(q1); q2 -= rintf(q2);
    const float vx = (float)((double)q0*s_cl[0] + (double)q1*s_cl[3] + (double)q2*s_cl[6]);
    const float vy = (float)((double)q0*s_cl[1] + (double)q1*s_cl[4] + (double)q2*s_cl[7]);
    const float vz = (float)((double)q0*s_cl[2] + (double)q1*s_cl[5] + (double)q2*s_cl[8]);
    const float rij = sqrtf(vx*vx + vy*vy + vz*vz);
    float h1[32];
    #pragma unroll
    for (int mm=0;mm<32;mm++) h1[mm] = silu_f(fmaf(rij, Wj1[mm], bj1[mm]));
    float o = bj3[0];
    for (int n=0;n<32;n++) {
      float a2 = bj2[n];
      #pragma unroll
      for (int mm=0;mm<32;mm++) a2 = fmaf(h1[mm], Wj2[mm*32+n], a2);
      o = fmaf(silu_f(a2), Wj3[n], o);
    }
    jpart += o;
  }
  #pragma unroll
  for (int off=32; off>=1; off>>=1) jpart += __shfl_xor(jpart, off, 64);
  if ((t & 63) == 0) s_red[t >> 6] = jpart;
  __syncthreads();

  // ---- stage 5: orbitals via f64 MFMA, f32 round into s_orb ----
  // wave wv: spin sp = wv>>1, col half nh = wv&1 (cols nh*128 .. nh*128+127)
  {
    const int sp = wv >> 1;
    const int nh = wv & 1;
    const float* __restrict__ Wo = sp ? W_dn : W_up;
    const float* __restrict__ bo = sp ? b_dn : b_up;
    const int arow = sp*16 + lr;
    #pragma unroll
    for (int p=0;p<2;p++) {
      f64x4 ac0={0.0,0.0,0.0,0.0}, ac1={0.0,0.0,0.0,0.0};
      f64x4 ac2={0.0,0.0,0.0,0.0}, ac3={0.0,0.0,0.0,0.0};
      const int cb = (nh*8 + p*4)*16 + lr;   // tiles at cb, cb+16, cb+32, cb+48
      #pragma unroll
      for (int kk=0;kk<16;kk++) {
        const int km = kk*4 + lq;
        const double af = (double)s_h[arow][km];
        const double q0 = (double)Wo[(size_t)km*256 + cb];
        const double q1 = (double)Wo[(size_t)km*256 + cb + 16];
        const double q2 = (double)Wo[(size_t)km*256 + cb + 32];
        const double q3 = (double)Wo[(size_t)km*256 + cb + 48];
        ac0 = MFMA64(af, q0, ac0);
        ac1 = MFMA64(af, q1, ac1);
        ac2 = MFMA64(af, q2, ac2);
        ac3 = MFMA64(af, q3, ac3);
      }
      const int row = lq*4;
      #pragma unroll
      for (int v=0;v<4;v++) {
        s_orb[sp][row+v][cb]      = (float)(ac0[v] + (double)bo[cb]);
        s_orb[sp][row+v][cb + 16] = (float)(ac1[v] + (double)bo[cb + 16]);
        s_orb[sp][row+v][cb + 32] = (float)(ac2[v] + (double)bo[cb + 32]);
        s_orb[sp][row+v][cb + 48] = (float)(ac3[v] + (double)bo[cb + 48]);
      }
    }
  }
  __syncthreads();

  // ---- stage 6: f64 LU on phi^T (det invariant), R4 LU body verbatim ----
  // thread t: det g = t>>4, LU-row r = t&15; a[j] = phi^T[r][j] = s_orb[sp][j][t]
  {
    const int g = t >> 4;
    const int r = t & 15;
    #pragma unroll 1
    for (int sp=0; sp<2; ++sp) {
      double a[16];
      #pragma unroll
      for (int j=0;j<16;j++) a[j] = (double)s_orb[sp][j][t];

      double prod = 1.0;
      int par = 0;
      #pragma unroll
      for (int k=0;k<16;k++) {
        double bv = (r >= k) ? fabs(a[k]) : -1.0;
        int bi = r;
        #pragma unroll
        for (int off=8; off>=1; off>>=1) {
          const double ov = __shfl_xor(bv, off, 16);
          const int    oi = __shfl_xor(bi, off, 16);
          if (ov > bv || (ov == bv && oi < bi)) { bv = ov; bi = oi; }
        }
        const int p = bi;
        par += (p != k) ? 1 : 0;
        #pragma unroll
        for (int j=k;j<16;j++) {
          const double rk = __shfl(a[j], k, 16);
          const double rp = __shfl(a[j], p, 16);
          a[j] = (r == k) ? rp : ((r == p) ? rk : a[j]);
        }
        const double piv = __shfl(a[k], k, 16);
        prod *= piv;
        const double f = (r > k && piv != 0.0) ? a[k]/piv : 0.0;
        #pragma unroll
        for (int j=k+1;j<16;j++) {
          const double rkj = __shfl(a[j], k, 16);
          a[j] = fma(-f, rkj, a[j]);
        }
      }
      if (r == 0) {
        s_lu[sp][g] = log(fabs(prod));
        const int neg = (prod < 0.0) ? 1 : 0;
        s_su[sp][g] = ((par + neg) & 1) ? -1.f : 1.f;
      }
    }
  }
  __syncthreads();

  // ---- stage 7: signed logsumexp combine (f64) ----
  if (t == 0) {
    double ww[KDET]; double mw = -1e300;
    #pragma unroll
    for (int k=0;k<KDET;k++) { ww[k] = (double)det_w[k]; mw = fmax(mw, ww[k]); }
    double sum = 0.0;
    #pragma unroll
    for (int k=0;k<KDET;k++) { ww[k] = exp(ww[k]-mw); sum += ww[k]; }
    const double inv_sum = 1.0/sum;
    double m = -1e300; double logs[KDET]; double sg[KDET];
    #pragma unroll
    for (int k=0;k<KDET;k++) {
      logs[k] = s_lu[0][k] + s_lu[1][k] + log(ww[k]*inv_sum + 1e-10);
      sg[k] = (double)(s_su[0][k] * s_su[1][k]);
      m = fmax(m, logs[k]);
    }
    double ssum = 0.0;
    #pragma unroll
    for (int k=0;k<KDET;k++) ssum += sg[k] * exp(logs[k]-m);
    const double jas = (double)jscale[0] * (double)(s_red[0]+s_red[1]+s_red[2]+s_red[3]);
    out[w] = (float)(jas + m + log(fabs(ssum) + 1e-30));
    out[N_WALK + w] = (ssum > 0.0) ? 1.f : ((ssum < 0.0) ? -1.f : 0.f);
  }
}

extern "C" void kernel_launch(void* const* d_in, const int* in_sizes, int n_in,
                              void* d_out, int out_size, void* d_ws, size_t ws_size,
                              hipStream_t stream) {
  const float* r_el  = (const float*)d_in[0];
  const float* cell  = (const float*)d_in[1];
  // d_in[2] = twist (unused by the reference)
  const float* W_e   = (const float*)d_in[3];
  const float* b_e   = (const float*)d_in[4];
  const float* W_pw  = (const float*)d_in[5];
  const float* b_pw  = (const float*)d_in[6];
  const float* W1    = (const float*)d_in[7];
  const float* b1    = (const float*)d_in[8];
  const float* W2    = (const float*)d_in[9];
  const float* b2    = (const float*)d_in[10];
  const float* ln_w  = (const float*)d_in[11];
  const float* ln_b  = (const float*)d_in[12];
  const float* W_up  = (const float*)d_in[13];
  const float* b_up  = (const float*)d_in[14];
  const float* W_dn  = (const float*)d_in[15];
  const float* b_dn  = (const float*)d_in[16];
  const float* det_w = (const float*)d_in[17];
  const float* Wj1   = (const float*)d_in[18];
  const float* bj1   = (const float*)d_in[19];
  const float* Wj2   = (const float*)d_in[20];
  const float* bj2   = (const float*)d_in[21];
  const float* Wj3   = (const float*)d_in[22];
  const float* bj3   = (const float*)d_in[23];
  const float* jsc   = (const float*)d_in[24];

  wf_kernel<<<N_WALK, 256, 0, stream>>>(
      r_el, cell, W_e, b_e, W_pw, b_pw, W1, b1, W2, b2, ln_w, ln_b,
      W_up, b_up, W_dn, b_dn, det_w, Wj1, bj1, Wj2, bj2, Wj3, bj3, jsc,
      (float*)d_out);
}

// Round 7
// 810.208 us; speedup vs baseline: 1.3574x; 1.0925x over previous
//
#include <hip/hip_runtime.h>

#define N_WALK 4096
#define N_EL   32
#define DIM    64
#define HPAD   68   // f32 row stride: 68%32=4 banks -> max 2-way conflict (free)
#define NLAY   3
#define KDET   16
#define NPAIR  496
#define TWO_PI_D 6.283185307179586476925286766559

using f64x4 = __attribute__((ext_vector_type(4))) double;

__device__ __forceinline__ double silu_d(double x) { return x / (1.0 + exp(-x)); }
__device__ __forceinline__ float  silu_f(float x)  { return x / (1.0f + expf(-x)); }

#define MFMA64(A, B, C) __builtin_amdgcn_mfma_f64_16x16x4f64((A), (B), (C), 0, 0, 0)

__global__ __launch_bounds__(256) void wf_kernel(
    const float* __restrict__ r_el,
    const float* __restrict__ cell,
    const float* __restrict__ W_e,  const float* __restrict__ b_e,
    const float* __restrict__ W_pw, const float* __restrict__ b_pw,
    const float* __restrict__ W1,   const float* __restrict__ b1,
    const float* __restrict__ W2,   const float* __restrict__ b2,
    const float* __restrict__ ln_w, const float* __restrict__ ln_b,
    const float* __restrict__ W_up, const float* __restrict__ b_up,
    const float* __restrict__ W_dn, const float* __restrict__ b_dn,
    const float* __restrict__ det_w,
    const float* __restrict__ Wj1,  const float* __restrict__ bj1,
    const float* __restrict__ Wj2,  const float* __restrict__ bj2,
    const float* __restrict__ Wj3,  const float* __restrict__ bj3,
    const float* __restrict__ jscale,
    float* __restrict__ out)
{
  __shared__ float s_linv[9];
  __shared__ float s_cl[9];
  __shared__ float s_r[N_EL][3];
  __shared__ float s_pw[N_EL][6];
  __shared__ float s_h[N_EL][HPAD];
  __shared__ float s_y[N_EL][HPAD];   // y, then v=h+delta
  __shared__ float s_hm[DIM];
  __shared__ double s_lu[2][KDET];
  __shared__ float  s_su[2][KDET];
  __shared__ float  s_red[4];

  const int t = threadIdx.x;
  const int w = blockIdx.x;
  const int wv = t >> 6;         // wave id 0..3
  const int l  = t & 63;
  const int lr = l & 15;         // row/col fragment index
  const int lq = l >> 4;         // k fragment index

  // ---- cell inverse: f64 compute, f32 round ----
  if (t == 0) {
    double m00=cell[0], m01=cell[1], m02=cell[2];
    double m10=cell[3], m11=cell[4], m12=cell[5];
    double m20=cell[6], m21=cell[7], m22=cell[8];
    double c00 = m11*m22 - m12*m21;
    double c10 = m12*m20 - m10*m22;
    double c20 = m10*m21 - m11*m20;
    double det = m00*c00 + m01*c10 + m02*c20;
    double id = 1.0/det;
    s_linv[0]=(float)(c00*id); s_linv[1]=(float)((m02*m21-m01*m22)*id); s_linv[2]=(float)((m01*m12-m02*m11)*id);
    s_linv[3]=(float)(c10*id); s_linv[4]=(float)((m00*m22-m02*m20)*id); s_linv[5]=(float)((m02*m10-m00*m12)*id);
    s_linv[6]=(float)(c20*id); s_linv[7]=(float)((m01*m20-m00*m21)*id); s_linv[8]=(float)((m00*m11-m01*m10)*id);
    #pragma unroll
    for (int i=0;i<9;i++) s_cl[i]=cell[i];
  }
  __syncthreads();

  // ---- stage 1: wrap + plane waves (f64 dots, f32 tensor boundaries) ----
  if (t < N_EL) {
    const float* rp = r_el + ((size_t)w * N_EL + t) * 3;
    const float rx = rp[0], ry = rp[1], rz = rp[2];
    float s0 = (float)((double)s_linv[0]*rx + (double)s_linv[1]*ry + (double)s_linv[2]*rz);
    float s1 = (float)((double)s_linv[3]*rx + (double)s_linv[4]*ry + (double)s_linv[5]*rz);
    float s2 = (float)((double)s_linv[6]*rx + (double)s_linv[7]*ry + (double)s_linv[8]*rz);
    s0 -= floorf(s0); s1 -= floorf(s1); s2 -= floorf(s2);
    const float wx = (float)((double)s0*s_cl[0] + (double)s1*s_cl[3] + (double)s2*s_cl[6]);
    const float wy = (float)((double)s0*s_cl[1] + (double)s1*s_cl[4] + (double)s2*s_cl[7]);
    const float wz = (float)((double)s0*s_cl[2] + (double)s1*s_cl[5] + (double)s2*s_cl[8]);
    s_r[t][0]=wx; s_r[t][1]=wy; s_r[t][2]=wz;
    const float u0 = (float)((double)s_linv[0]*wx + (double)s_linv[1]*wy + (double)s_linv[2]*wz);
    const float u1 = (float)((double)s_linv[3]*wx + (double)s_linv[4]*wy + (double)s_linv[5]*wz);
    const float u2 = (float)((double)s_linv[6]*wx + (double)s_linv[7]*wy + (double)s_linv[8]*wz);
    double sn, cs;
    sincos(TWO_PI_D*(double)u0, &sn, &cs); s_pw[t][0]=(float)sn; s_pw[t][3]=(float)cs;
    sincos(TWO_PI_D*(double)u1, &sn, &cs); s_pw[t][1]=(float)sn; s_pw[t][4]=(float)cs;
    sincos(TWO_PI_D*(double)u2, &sn, &cs); s_pw[t][2]=(float)sn; s_pw[t][5]=(float)cs;
  }
  __syncthreads();

  // ---- stage 2: h0 (f64 acc -> f32 store) ----
  {
    const int e = t >> 3, db = (t & 7) * 8;
    const double rx=s_r[e][0], ry=s_r[e][1], rz=s_r[e][2];
    const double p0=s_pw[e][0],p1=s_pw[e][1],p2=s_pw[e][2];
    const double p3=s_pw[e][3],p4=s_pw[e][4],p5=s_pw[e][5];
    #pragma unroll
    for (int u=0;u<8;u++) {
      const int d = db+u;
      double acc = (double)b_e[d] + (double)b_pw[d];
      acc = fma(rx, (double)W_e[0*DIM+d], acc);
      acc = fma(ry, (double)W_e[1*DIM+d], acc);
      acc = fma(rz, (double)W_e[2*DIM+d], acc);
      acc = fma(p0, (double)W_pw[0*DIM+d], acc);
      acc = fma(p1, (double)W_pw[1*DIM+d], acc);
      acc = fma(p2, (double)W_pw[2*DIM+d], acc);
      acc = fma(p3, (double)W_pw[3*DIM+d], acc);
      acc = fma(p4, (double)W_pw[4*DIM+d], acc);
      acc = fma(p5, (double)W_pw[5*DIM+d], acc);
      s_h[e][d] = (float)acc;
    }
  }
  __syncthreads();

  // ---- stage 3: interaction layers via f64 MFMA (R6-validated) ----
  for (int L = 0; L < NLAY; ++L) {
    const float* __restrict__ w1p = W1 + (size_t)L*192*DIM;
    const float* __restrict__ w2p = W2 + (size_t)L*DIM*DIM;

    if (t < DIM) {
      double s = 0.0;
      #pragma unroll 8
      for (int e=0;e<N_EL;e++) s += (double)s_h[e][t];
      s_hm[t] = (float)(s * (1.0/N_EL));
    }
    __syncthreads();

    const int m  = wv & 1;
    const int nb = (wv >> 1) * 2;
    const int ea = m*16 + lr;        // A-fragment row (electron)
    const int c0 = nb*16 + lr;       // D/B column of tile 0 (tile 1 = c0+16)
    const int er = m*16 + lq*4;      // D row base

    // --- y = silu([h, hm, h*hm] @ W1 + b1) ---
    {
      f64x4 a0 = {0.0,0.0,0.0,0.0}, a1 = {0.0,0.0,0.0,0.0};
      #pragma unroll
      for (int kk=0;kk<16;kk++) {              // K seg 0: x = h
        const int km = kk*4 + lq;
        const double af = (double)s_h[ea][km];
        const double q0 = (double)w1p[km*DIM + c0];
        const double q1 = (double)w1p[km*DIM + c0 + 16];
        a0 = MFMA64(af, q0, a0);
        a1 = MFMA64(af, q1, a1);
      }
      #pragma unroll
      for (int kk=0;kk<16;kk++) {              // K seg 1: x = hm
        const int km = kk*4 + lq;
        const double af = (double)s_hm[km];
        const double q0 = (double)w1p[(64+km)*DIM + c0];
        const double q1 = (double)w1p[(64+km)*DIM + c0 + 16];
        a0 = MFMA64(af, q0, a0);
        a1 = MFMA64(af, q1, a1);
      }
      #pragma unroll
      for (int kk=0;kk<16;kk++) {              // K seg 2: x = h*hm (f32 product)
        const int km = kk*4 + lq;
        const double af = (double)(s_h[ea][km] * s_hm[km]);
        const double q0 = (double)w1p[(128+km)*DIM + c0];
        const double q1 = (double)w1p[(128+km)*DIM + c0 + 16];
        a0 = MFMA64(af, q0, a0);
        a1 = MFMA64(af, q1, a1);
      }
      #pragma unroll
      for (int v=0;v<4;v++) {
        const float p0 = (float)(a0[v] + (double)b1[L*DIM + c0]);      // np pre-act
        const float p1 = (float)(a1[v] + (double)b1[L*DIM + c0 + 16]);
        s_y[er+v][c0]      = (float)silu_d((double)p0);
        s_y[er+v][c0 + 16] = (float)silu_d((double)p1);
      }
    }
    __syncthreads();

    // --- delta = y @ W2 + b2 ; v = h + delta ---
    {
      f64x4 a0 = {0.0,0.0,0.0,0.0}, a1 = {0.0,0.0,0.0,0.0};
      #pragma unroll
      for (int kk=0;kk<16;kk++) {
        const int km = kk*4 + lq;
        const double af = (double)s_y[ea][km];
        const double q0 = (double)w2p[km*DIM + c0];
        const double q1 = (double)w2p[km*DIM + c0 + 16];
        a0 = MFMA64(af, q0, a0);
        a1 = MFMA64(af, q1, a1);
      }
      __syncthreads();   // all waves done READING s_y; now overwrite with v
      #pragma unroll
      for (int v=0;v<4;v++) {
        const float d0 = (float)(a0[v] + (double)b2[L*DIM + c0]);      // np delta
        const float d1 = (float)(a1[v] + (double)b2[L*DIM + c0 + 16]);
        s_y[er+v][c0]      = s_h[er+v][c0]      + d0;                  // np h+delta
        s_y[er+v][c0 + 16] = s_h[er+v][c0 + 16] + d1;
      }
    }
    __syncthreads();

    // --- LayerNorm: stats f64, tensors f32 (reads s_y, writes s_h) ---
    {
      const int e = t >> 3, db = (t & 7) * 8;
      float v[8];
      double ps=0.0, pss=0.0;
      #pragma unroll
      for (int u=0;u<8;u++) {
        v[u] = s_y[e][db+u];
        ps += (double)v[u]; pss += (double)v[u]*(double)v[u];
      }
      #pragma unroll
      for (int off=4; off>=1; off>>=1) {
        ps  += __shfl_xor(ps,  off, 8);
        pss += __shfl_xor(pss, off, 8);
      }
      const double mu = ps * (1.0/DIM);
      double var = pss * (1.0/DIM) - mu*mu;
      var = fmax(var, 0.0);
      const double rstd = 1.0 / sqrt(var + 1e-5);
      #pragma unroll
      for (int u=0;u<8;u++) {
        const int d = db+u;
        s_h[e][d] = (float)(((double)v[u]-mu)*rstd*(double)ln_w[L*DIM+d] + (double)ln_b[L*DIM+d]);
      }
    }
    __syncthreads();
  }

  // ---- stage 4: Jastrow (R4 verbatim) ----
  float jpart = 0.f;
  for (int p = t; p < NPAIR; p += 256) {
    int i = 0, rem = p;
    while (rem >= (N_EL-1) - i) { rem -= (N_EL-1) - i; ++i; }
    const int j = i + 1 + rem;
    const float dx = s_r[i][0]-s_r[j][0];
    const float dy = s_r[i][1]-s_r[j][1];
    const float dz = s_r[i][2]-s_r[j][2];
    float q0 = (float)((double)s_linv[0]*dx + (double)s_linv[1]*dy + (double)s_linv[2]*dz);
    float q1 = (float)((double)s_linv[3]*dx + (double)s_linv[4]*dy + (double)s_linv[5]*dz);
    float q2 = (float)((double)s_linv[6]*dx + (double)s_linv[7]*dy + (double)s_linv[8]*dz);
    q0 -= rintf(q0); q1 -= rintf(q1); q2 -= rintf(q2);
    const float vx = (float)((double)q0*s_cl[0] + (double)q1*s_cl[3] + (double)q2*s_cl[6]);
    const float vy = (float)((double)q0*s_cl[1] + (double)q1*s_cl[4] + (double)q2*s_cl[7]);
    const float vz = (float)((double)q0*s_cl[2] + (double)q1*s_cl[5] + (double)q2*s_cl[8]);
    const float rij = sqrtf(vx*vx + vy*vy + vz*vz);
    float h1[32];
    #pragma unroll
    for (int mm=0;mm<32;mm++) h1[mm] = silu_f(fmaf(rij, Wj1[mm], bj1[mm]));
    float o = bj3[0];
    for (int n=0;n<32;n++) {
      float a2 = bj2[n];
      #pragma unroll
      for (int mm=0;mm<32;mm++) a2 = fmaf(h1[mm], Wj2[mm*32+n], a2);
      o = fmaf(silu_f(a2), Wj3[n], o);
    }
    jpart += o;
  }
  #pragma unroll
  for (int off=32; off>=1; off>>=1) jpart += __shfl_xor(jpart, off, 64);
  if ((t & 63) == 0) s_red[t >> 6] = jpart;
  __syncthreads();

  // ---- stage 5+6: R4-verbatim row-owned orbitals (f64 acc -> f32 round) +
  //      f64 LU with physical row swaps. No LDS needed. ----
  {
    const int g = t >> 4;
    const int r = t & 15;
    const int c0 = g * 16;
    #pragma unroll 1
    for (int sp=0; sp<2; ++sp) {
      const float* __restrict__ Wo = sp ? W_dn : W_up;
      const float* __restrict__ bo = sp ? b_dn : b_up;
      const int hrow = sp*16 + r;
      double acc[16];
      #pragma unroll
      for (int j=0;j<16;j++) acc[j] = (double)bo[c0+j];
      for (int d=0; d<DIM; d++) {
        const double hv = (double)s_h[hrow][d];
        const float* wr = Wo + (size_t)d*256 + c0;
        const float4 w0 = *(const float4*)(wr);
        const float4 w1v = *(const float4*)(wr+4);
        const float4 w2v = *(const float4*)(wr+8);
        const float4 w3v = *(const float4*)(wr+12);
        acc[0] =fma(hv,(double)w0.x, acc[0]);  acc[1] =fma(hv,(double)w0.y, acc[1]);
        acc[2] =fma(hv,(double)w0.z, acc[2]);  acc[3] =fma(hv,(double)w0.w, acc[3]);
        acc[4] =fma(hv,(double)w1v.x,acc[4]);  acc[5] =fma(hv,(double)w1v.y,acc[5]);
        acc[6] =fma(hv,(double)w1v.z,acc[6]);  acc[7] =fma(hv,(double)w1v.w,acc[7]);
        acc[8] =fma(hv,(double)w2v.x,acc[8]);  acc[9] =fma(hv,(double)w2v.y,acc[9]);
        acc[10]=fma(hv,(double)w2v.z,acc[10]); acc[11]=fma(hv,(double)w2v.w,acc[11]);
        acc[12]=fma(hv,(double)w3v.x,acc[12]); acc[13]=fma(hv,(double)w3v.y,acc[13]);
        acc[14]=fma(hv,(double)w3v.z,acc[14]); acc[15]=fma(hv,(double)w3v.w,acc[15]);
      }
      double a[16];
      #pragma unroll
      for (int j=0;j<16;j++) a[j] = (double)(float)acc[j];   // f32 round = np orb

      // --- LU, partial pivoting with physical row swaps (R4 verbatim) ---
      double prod = 1.0;
      int par = 0;
      #pragma unroll
      for (int k=0;k<16;k++) {
        double bv = (r >= k) ? fabs(a[k]) : -1.0;
        int bi = r;
        #pragma unroll
        for (int off=8; off>=1; off>>=1) {
          const double ov = __shfl_xor(bv, off, 16);
          const int    oi = __shfl_xor(bi, off, 16);
          if (ov > bv || (ov == bv && oi < bi)) { bv = ov; bi = oi; }
        }
        const int p = bi;
        par += (p != k) ? 1 : 0;
        #pragma unroll
        for (int j=k;j<16;j++) {
          const double rk = __shfl(a[j], k, 16);
          const double rp = __shfl(a[j], p, 16);
          a[j] = (r == k) ? rp : ((r == p) ? rk : a[j]);
        }
        const double piv = __shfl(a[k], k, 16);
        prod *= piv;
        const double f = (r > k && piv != 0.0) ? a[k]/piv : 0.0;
        #pragma unroll
        for (int j=k+1;j<16;j++) {
          const double rkj = __shfl(a[j], k, 16);
          a[j] = fma(-f, rkj, a[j]);
        }
      }
      if (r == 0) {
        s_lu[sp][g] = log(fabs(prod));
        const int neg = (prod < 0.0) ? 1 : 0;
        s_su[sp][g] = ((par + neg) & 1) ? -1.f : 1.f;
      }
    }
  }
  __syncthreads();

  // ---- stage 7: signed logsumexp combine (f64) ----
  if (t == 0) {
    double ww[KDET]; double mw = -1e300;
    #pragma unroll
    for (int k=0;k<KDET;k++) { ww[k] = (double)det_w[k]; mw = fmax(mw, ww[k]); }
    double sum = 0.0;
    #pragma unroll
    for (int k=0;k<KDET;k++) { ww[k] = exp(ww[k]-mw); sum += ww[k]; }
    const double inv_sum = 1.0/sum;
    double m = -1e300; double logs[KDET]; double sg[KDET];
    #pragma unroll
    for (int k=0;k<KDET;k++) {
      logs[k] = s_lu[0][k] + s_lu[1][k] + log(ww[k]*inv_sum + 1e-10);
      sg[k] = (double)(s_su[0][k] * s_su[1][k]);
      m = fmax(m, logs[k]);
    }
    double ssum = 0.0;
    #pragma unroll
    for (int k=0;k<KDET;k++) ssum += sg[k] * exp(logs[k]-m);
    const double jas = (double)jscale[0] * (double)(s_red[0]+s_red[1]+s_red[2]+s_red[3]);
    out[w] = (float)(jas + m + log(fabs(ssum) + 1e-30));
    out[N_WALK + w] = (ssum > 0.0) ? 1.f : ((ssum < 0.0) ? -1.f : 0.f);
  }
}

extern "C" void kernel_launch(void* const* d_in, const int* in_sizes, int n_in,
                              void* d_out, int out_size, void* d_ws, size_t ws_size,
                              hipStream_t stream) {
  const float* r_el  = (const float*)d_in[0];
  const float* cell  = (const float*)d_in[1];
  // d_in[2] = twist (unused by the reference)
  const float* W_e   = (const float*)d_in[3];
  const float* b_e   = (const float*)d_in[4];
  const float* W_pw  = (const float*)d_in[5];
  const float* b_pw  = (const float*)d_in[6];
  const float* W1    = (const float*)d_in[7];
  const float* b1    = (const float*)d_in[8];
  const float* W2    = (const float*)d_in[9];
  const float* b2    = (const float*)d_in[10];
  const float* ln_w  = (const float*)d_in[11];
  const float* ln_b  = (const float*)d_in[12];
  const float* W_up  = (const float*)d_in[13];
  const float* b_up  = (const float*)d_in[14];
  const float* W_dn  = (const float*)d_in[15];
  const float* b_dn  = (const float*)d_in[16];
  const float* det_w = (const float*)d_in[17];
  const float* Wj1   = (const float*)d_in[18];
  const float* bj1   = (const float*)d_in[19];
  const float* Wj2   = (const float*)d_in[20];
  const float* bj2   = (const float*)d_in[21];
  const float* Wj3   = (const float*)d_in[22];
  const float* bj3   = (const float*)d_in[23];
  const float* jsc   = (const float*)d_in[24];

  wf_kernel<<<N_WALK, 256, 0, stream>>>(
      r_el, cell, W_e, b_e, W_pw, b_pw, W1, b1, W2, b2, ln_w, ln_b,
      W_up, b_up, W_dn, b_dn, det_w, Wj1, bj1, Wj2, bj2, Wj3, bj3, jsc,
      (float*)d_out);
}

// Round 8
// 691.269 us; speedup vs baseline: 1.5910x; 1.1721x over previous
//
#include <hip/hip_runtime.h>

#define N_WALK 4096
#define N_EL   32
#define DIM    64
#define HPAD   68   // f32 row stride: 68%32=4 banks -> max 2-way conflict (free)
#define NLAY   3
#define KDET   16
#define NPAIR  496
#define TWO_PI_D 6.283185307179586476925286766559

using f64x4 = __attribute__((ext_vector_type(4))) double;

#define MFMA64(A, B, C) __builtin_amdgcn_mfma_f64_16x16x4f64((A), (B), (C), 0, 0, 0)

// fast f64 exp, rel err ~3e-13 for |x| <= 60 (enough: f32 boundary rounding
// identical to libm except ~1e-6 probability per element)
__device__ __forceinline__ double exp_d(double x) {
  const double LOG2E  = 1.4426950408889634074;
  const double LN2_HI = 6.93147180369123816490e-01;
  const double LN2_LO = 1.90821492927058770002e-10;
  const double nf = rint(x * LOG2E);
  double r = fma(-nf, LN2_HI, x);
  r = fma(-nf, LN2_LO, r);
  double p = 1.0/3628800.0;
  p = fma(p, r, 1.0/362880.0);
  p = fma(p, r, 1.0/40320.0);
  p = fma(p, r, 1.0/5040.0);
  p = fma(p, r, 1.0/720.0);
  p = fma(p, r, 1.0/120.0);
  p = fma(p, r, 1.0/24.0);
  p = fma(p, r, 1.0/6.0);
  p = fma(p, r, 0.5);
  p = fma(p, r, 1.0);
  p = fma(p, r, 1.0);
  const long long bits = ((long long)((int)nf + 1023)) << 52;
  return p * __longlong_as_double(bits);
}

// silu with Newton-recip division (rel err ~1e-14); graceful at extremes
__device__ __forceinline__ double silu_d(double x) {
  const double d = 1.0 + exp_d(-x);
  const double q0 = (double)(1.0f / (float)d);
  double q = q0 * (2.0 - d * q0);
  q = q * (2.0 - d * q);
  return x * q;
}
__device__ __forceinline__ float silu_f(float x) { return x / (1.0f + expf(-x)); }

__global__ __launch_bounds__(256) void wf_kernel(
    const float* __restrict__ r_el,
    const float* __restrict__ cell,
    const float* __restrict__ W_e,  const float* __restrict__ b_e,
    const float* __restrict__ W_pw, const float* __restrict__ b_pw,
    const float* __restrict__ W1,   const float* __restrict__ b1,
    const float* __restrict__ W2,   const float* __restrict__ b2,
    const float* __restrict__ ln_w, const float* __restrict__ ln_b,
    const float* __restrict__ W_up, const float* __restrict__ b_up,
    const float* __restrict__ W_dn, const float* __restrict__ b_dn,
    const float* __restrict__ det_w,
    const float* __restrict__ Wj1,  const float* __restrict__ bj1,
    const float* __restrict__ Wj2,  const float* __restrict__ bj2,
    const float* __restrict__ Wj3,  const float* __restrict__ bj3,
    const float* __restrict__ jscale,
    float* __restrict__ out)
{
  __shared__ float s_linv[9];
  __shared__ float s_cl[9];
  __shared__ float s_r[N_EL][3];
  __shared__ float s_pw[N_EL][6];
  __shared__ float s_h[N_EL][HPAD];
  // union buffer: stage-3 s_y [32][HPAD]=2176 floats; stage-5 phi [16][257]=4112 floats
  __shared__ float s_u[16*257];
  __shared__ float s_hm[DIM];
  __shared__ double s_lu[2][KDET];
  __shared__ float  s_su[2][KDET];
  __shared__ float  s_red[4];
#define SY(e,d)   s_u[(e)*HPAD + (d)]
#define SORB(j,c) s_u[(j)*257 + (c)]

  const int t = threadIdx.x;
  const int w = blockIdx.x;
  const int wv = t >> 6;         // wave id 0..3
  const int l  = t & 63;
  const int lr = l & 15;         // row/col fragment index
  const int lq = l >> 4;         // k fragment index

  // ---- cell inverse: f64 compute, f32 round ----
  if (t == 0) {
    double m00=cell[0], m01=cell[1], m02=cell[2];
    double m10=cell[3], m11=cell[4], m12=cell[5];
    double m20=cell[6], m21=cell[7], m22=cell[8];
    double c00 = m11*m22 - m12*m21;
    double c10 = m12*m20 - m10*m22;
    double c20 = m10*m21 - m11*m20;
    double det = m00*c00 + m01*c10 + m02*c20;
    double id = 1.0/det;
    s_linv[0]=(float)(c00*id); s_linv[1]=(float)((m02*m21-m01*m22)*id); s_linv[2]=(float)((m01*m12-m02*m11)*id);
    s_linv[3]=(float)(c10*id); s_linv[4]=(float)((m00*m22-m02*m20)*id); s_linv[5]=(float)((m02*m10-m00*m12)*id);
    s_linv[6]=(float)(c20*id); s_linv[7]=(float)((m01*m20-m00*m21)*id); s_linv[8]=(float)((m00*m11-m01*m10)*id);
    #pragma unroll
    for (int i=0;i<9;i++) s_cl[i]=cell[i];
  }
  __syncthreads();

  // ---- stage 1: wrap + plane waves (f64 dots, f32 tensor boundaries) ----
  if (t < N_EL) {
    const float* rp = r_el + ((size_t)w * N_EL + t) * 3;
    const float rx = rp[0], ry = rp[1], rz = rp[2];
    float s0 = (float)((double)s_linv[0]*rx + (double)s_linv[1]*ry + (double)s_linv[2]*rz);
    float s1 = (float)((double)s_linv[3]*rx + (double)s_linv[4]*ry + (double)s_linv[5]*rz);
    float s2 = (float)((double)s_linv[6]*rx + (double)s_linv[7]*ry + (double)s_linv[8]*rz);
    s0 -= floorf(s0); s1 -= floorf(s1); s2 -= floorf(s2);
    const float wx = (float)((double)s0*s_cl[0] + (double)s1*s_cl[3] + (double)s2*s_cl[6]);
    const float wy = (float)((double)s0*s_cl[1] + (double)s1*s_cl[4] + (double)s2*s_cl[7]);
    const float wz = (float)((double)s0*s_cl[2] + (double)s1*s_cl[5] + (double)s2*s_cl[8]);
    s_r[t][0]=wx; s_r[t][1]=wy; s_r[t][2]=wz;
    const float u0 = (float)((double)s_linv[0]*wx + (double)s_linv[1]*wy + (double)s_linv[2]*wz);
    const float u1 = (float)((double)s_linv[3]*wx + (double)s_linv[4]*wy + (double)s_linv[5]*wz);
    const float u2 = (float)((double)s_linv[6]*wx + (double)s_linv[7]*wy + (double)s_linv[8]*wz);
    double sn, cs;
    sincos(TWO_PI_D*(double)u0, &sn, &cs); s_pw[t][0]=(float)sn; s_pw[t][3]=(float)cs;
    sincos(TWO_PI_D*(double)u1, &sn, &cs); s_pw[t][1]=(float)sn; s_pw[t][4]=(float)cs;
    sincos(TWO_PI_D*(double)u2, &sn, &cs); s_pw[t][2]=(float)sn; s_pw[t][5]=(float)cs;
  }
  __syncthreads();

  // ---- stage 2: h0 (f64 acc -> f32 store) ----
  {
    const int e = t >> 3, db = (t & 7) * 8;
    const double rx=s_r[e][0], ry=s_r[e][1], rz=s_r[e][2];
    const double p0=s_pw[e][0],p1=s_pw[e][1],p2=s_pw[e][2];
    const double p3=s_pw[e][3],p4=s_pw[e][4],p5=s_pw[e][5];
    #pragma unroll
    for (int u=0;u<8;u++) {
      const int d = db+u;
      double acc = (double)b_e[d] + (double)b_pw[d];
      acc = fma(rx, (double)W_e[0*DIM+d], acc);
      acc = fma(ry, (double)W_e[1*DIM+d], acc);
      acc = fma(rz, (double)W_e[2*DIM+d], acc);
      acc = fma(p0, (double)W_pw[0*DIM+d], acc);
      acc = fma(p1, (double)W_pw[1*DIM+d], acc);
      acc = fma(p2, (double)W_pw[2*DIM+d], acc);
      acc = fma(p3, (double)W_pw[3*DIM+d], acc);
      acc = fma(p4, (double)W_pw[4*DIM+d], acc);
      acc = fma(p5, (double)W_pw[5*DIM+d], acc);
      s_h[e][d] = (float)acc;
    }
  }
  __syncthreads();

  // ---- stage 3: interaction layers via f64 MFMA (R6/R7-validated) ----
  for (int L = 0; L < NLAY; ++L) {
    const float* __restrict__ w1p = W1 + (size_t)L*192*DIM;
    const float* __restrict__ w2p = W2 + (size_t)L*DIM*DIM;

    if (t < DIM) {
      double s = 0.0;
      #pragma unroll 8
      for (int e=0;e<N_EL;e++) s += (double)s_h[e][t];
      s_hm[t] = (float)(s * (1.0/N_EL));
    }
    __syncthreads();

    const int m  = wv & 1;
    const int nb = (wv >> 1) * 2;
    const int ea = m*16 + lr;        // A-fragment row (electron)
    const int c0 = nb*16 + lr;       // D/B column of tile 0 (tile 1 = c0+16)
    const int er = m*16 + lq*4;      // D row base

    // --- y = silu([h, hm, h*hm] @ W1 + b1) ---
    {
      f64x4 a0 = {0.0,0.0,0.0,0.0}, a1 = {0.0,0.0,0.0,0.0};
      #pragma unroll
      for (int kk=0;kk<16;kk++) {              // K seg 0: x = h
        const int km = kk*4 + lq;
        const double af = (double)s_h[ea][km];
        const double q0 = (double)w1p[km*DIM + c0];
        const double q1 = (double)w1p[km*DIM + c0 + 16];
        a0 = MFMA64(af, q0, a0);
        a1 = MFMA64(af, q1, a1);
      }
      #pragma unroll
      for (int kk=0;kk<16;kk++) {              // K seg 1: x = hm
        const int km = kk*4 + lq;
        const double af = (double)s_hm[km];
        const double q0 = (double)w1p[(64+km)*DIM + c0];
        const double q1 = (double)w1p[(64+km)*DIM + c0 + 16];
        a0 = MFMA64(af, q0, a0);
        a1 = MFMA64(af, q1, a1);
      }
      #pragma unroll
      for (int kk=0;kk<16;kk++) {              // K seg 2: x = h*hm (f32 product)
        const int km = kk*4 + lq;
        const double af = (double)(s_h[ea][km] * s_hm[km]);
        const double q0 = (double)w1p[(128+km)*DIM + c0];
        const double q1 = (double)w1p[(128+km)*DIM + c0 + 16];
        a0 = MFMA64(af, q0, a0);
        a1 = MFMA64(af, q1, a1);
      }
      #pragma unroll
      for (int v=0;v<4;v++) {
        const float p0 = (float)(a0[v] + (double)b1[L*DIM + c0]);      // np pre-act
        const float p1 = (float)(a1[v] + (double)b1[L*DIM + c0 + 16]);
        SY(er+v, c0)      = (float)silu_d((double)p0);
        SY(er+v, c0 + 16) = (float)silu_d((double)p1);
      }
    }
    __syncthreads();

    // --- delta = y @ W2 + b2 ; v = h + delta ---
    {
      f64x4 a0 = {0.0,0.0,0.0,0.0}, a1 = {0.0,0.0,0.0,0.0};
      #pragma unroll
      for (int kk=0;kk<16;kk++) {
        const int km = kk*4 + lq;
        const double af = (double)SY(ea, km);
        const double q0 = (double)w2p[km*DIM + c0];
        const double q1 = (double)w2p[km*DIM + c0 + 16];
        a0 = MFMA64(af, q0, a0);
        a1 = MFMA64(af, q1, a1);
      }
      __syncthreads();   // all waves done READING s_y; now overwrite with v
      #pragma unroll
      for (int v=0;v<4;v++) {
        const float d0 = (float)(a0[v] + (double)b2[L*DIM + c0]);      // np delta
        const float d1 = (float)(a1[v] + (double)b2[L*DIM + c0 + 16]);
        SY(er+v, c0)      = s_h[er+v][c0]      + d0;                   // np h+delta
        SY(er+v, c0 + 16) = s_h[er+v][c0 + 16] + d1;
      }
    }
    __syncthreads();

    // --- LayerNorm: stats f64 (Newton rstd), tensors f32 ---
    {
      const int e = t >> 3, db = (t & 7) * 8;
      float v[8];
      double ps=0.0, pss=0.0;
      #pragma unroll
      for (int u=0;u<8;u++) {
        v[u] = SY(e, db+u);
        ps += (double)v[u]; pss += (double)v[u]*(double)v[u];
      }
      #pragma unroll
      for (int off=4; off>=1; off>>=1) {
        ps  += __shfl_xor(ps,  off, 8);
        pss += __shfl_xor(pss, off, 8);
      }
      const double mu = ps * (1.0/DIM);
      double var = pss * (1.0/DIM) - mu*mu;
      var = fmax(var, 0.0);
      const double s = var + 1e-5;
      double rstd = (double)rsqrtf((float)s);
      rstd = rstd * (1.5 - 0.5*s*rstd*rstd);
      rstd = rstd * (1.5 - 0.5*s*rstd*rstd);
      #pragma unroll
      for (int u=0;u<8;u++) {
        const int d = db+u;
        s_h[e][d] = (float)(((double)v[u]-mu)*rstd*(double)ln_w[L*DIM+d] + (double)ln_b[L*DIM+d]);
      }
    }
    __syncthreads();
  }

  // ---- stage 4: Jastrow ----
  float jpart = 0.f;
  for (int p = t; p < NPAIR; p += 256) {
    int i = 0, rem = p;
    while (rem >= (N_EL-1) - i) { rem -= (N_EL-1) - i; ++i; }
    const int j = i + 1 + rem;
    const float dx = s_r[i][0]-s_r[j][0];
    const float dy = s_r[i][1]-s_r[j][1];
    const float dz = s_r[i][2]-s_r[j][2];
    float q0 = (float)((double)s_linv[0]*dx + (double)s_linv[1]*dy + (double)s_linv[2]*dz);
    float q1 = (float)((double)s_linv[3]*dx + (double)s_linv[4]*dy + (double)s_linv[5]*dz);
    float q2 = (float)((double)s_linv[6]*dx + (double)s_linv[7]*dy + (double)s_linv[8]*dz);
    q0 -= rintf(q0); q1 -= rintf(q1); q2 -= rintf(q2);
    const float vx = (float)((double)q0*s_cl[0] + (double)q1*s_cl[3] + (double)q2*s_cl[6]);
    const float vy = (float)((double)q0*s_cl[1] + (double)q1*s_cl[4] + (double)q2*s_cl[7]);
    const float vz = (float)((double)q0*s_cl[2] + (double)q1*s_cl[5] + (double)q2*s_cl[8]);
    const float rij = sqrtf(vx*vx + vy*vy + vz*vz);
    float h1[32];
    #pragma unroll
    for (int mm=0;mm<32;mm++) h1[mm] = silu_f(fmaf(rij, Wj1[mm], bj1[mm]));
    float o = bj3[0];
    for (int n=0;n<32;n++) {
      float a2 = bj2[n];
      #pragma unroll
      for (int mm=0;mm<32;mm++) a2 = fmaf(h1[mm], Wj2[mm*32+n], a2);
      o = fmaf(silu_f(a2), Wj3[n], o);
    }
    jpart += o;
  }
  #pragma unroll
  for (int off=32; off>=1; off>>=1) jpart += __shfl_xor(jpart, off, 64);
  if ((t & 63) == 0) s_red[t >> 6] = jpart;
  __syncthreads();

  // ---- stage 5+6: orbitals via f64 MFMA into padded LDS (per spin), then LU ----
  // wave wv computes dets 4wv..4wv+3 of each spin; phi staged f32 at stride 257
  // (LU column reads conflict-free). LU: det g = t>>4, col r = t&15 (phi^T).
  {
    const int g4 = wv * 4;
    const int g  = t >> 4;
    const int r  = t & 15;
    #pragma unroll 1
    for (int sp=0; sp<2; ++sp) {
      const float* __restrict__ Wo = sp ? W_dn : W_up;
      const float* __restrict__ bo = sp ? b_dn : b_up;
      const int arow = sp*16 + lr;     // A row = lr, A k = lq
      #pragma unroll 1
      for (int gi=0; gi<4; ++gi) {
        const int cb = (g4 + gi)*16 + lr;      // B/D column
        f64x4 ac = {0.0,0.0,0.0,0.0};
        #pragma unroll
        for (int kk=0;kk<16;kk++) {
          const int km = kk*4 + lq;
          const double av = (double)s_h[arow][km];
          const double bv = (double)Wo[(size_t)km*256 + cb];
          ac = MFMA64(av, bv, ac);
        }
        const int row = lq*4;
        #pragma unroll
        for (int v=0;v<4;v++)
          SORB(row+v, cb) = (float)(ac[v] + (double)bo[cb]);   // f32 round = np orb
      }
      __syncthreads();

      double a[16];
      #pragma unroll
      for (int j=0;j<16;j++) a[j] = (double)SORB(j, t);

      // --- LU, partial pivoting with physical row swaps (R4/R7-validated;
      //     argmax on f32 magnitudes — selection only, parity stays exact) ---
      double prod = 1.0;
      int par = 0;
      #pragma unroll
      for (int k=0;k<16;k++) {
        float bv = (r >= k) ? (float)fabs(a[k]) : -1.0f;
        int bi = r;
        #pragma unroll
        for (int off=8; off>=1; off>>=1) {
          const float ov = __shfl_xor(bv, off, 16);
          const int   oi = __shfl_xor(bi, off, 16);
          if (ov > bv || (ov == bv && oi < bi)) { bv = ov; bi = oi; }
        }
        const int p = bi;
        par += (p != k) ? 1 : 0;
        #pragma unroll
        for (int j=k;j<16;j++) {
          const double rk = __shfl(a[j], k, 16);
          const double rp = __shfl(a[j], p, 16);
          a[j] = (r == k) ? rp : ((r == p) ? rk : a[j]);
        }
        const double piv = __shfl(a[k], k, 16);
        prod *= piv;
        const double f = (r > k && piv != 0.0) ? a[k]/piv : 0.0;
        #pragma unroll
        for (int j=k+1;j<16;j++) {
          const double rkj = __shfl(a[j], k, 16);
          a[j] = fma(-f, rkj, a[j]);
        }
      }
      if (r == 0) {
        s_lu[sp][g] = log(fabs(prod));
        const int neg = (prod < 0.0) ? 1 : 0;
        s_su[sp][g] = ((par + neg) & 1) ? -1.f : 1.f;
      }
      __syncthreads();
    }
  }

  // ---- stage 7: signed logsumexp combine (f64, 16-thread parallel) ----
  if (t < 16) {
    const int k = t;
    const double wwk = (double)det_w[k];
    double mw = wwk;
    #pragma unroll
    for (int off=8; off>=1; off>>=1) mw = fmax(mw, __shfl_xor(mw, off, 16));
    const double ew = exp_d(wwk - mw);
    double sum = ew;
    #pragma unroll
    for (int off=8; off>=1; off>>=1) sum += __shfl_xor(sum, off, 16);
    const double lg = s_lu[0][k] + s_lu[1][k] + log(ew/sum + 1e-10);
    const double sg = (double)(s_su[0][k] * s_su[1][k]);
    double m = lg;
    #pragma unroll
    for (int off=8; off>=1; off>>=1) m = fmax(m, __shfl_xor(m, off, 16));
    double ssum = sg * exp_d(lg - m);
    #pragma unroll
    for (int off=8; off>=1; off>>=1) ssum += __shfl_xor(ssum, off, 16);
    if (t == 0) {
      const double jas = (double)jscale[0] * (double)(s_red[0]+s_red[1]+s_red[2]+s_red[3]);
      out[w] = (float)(jas + m + log(fabs(ssum) + 1e-30));
      out[N_WALK + w] = (ssum > 0.0) ? 1.f : ((ssum < 0.0) ? -1.f : 0.f);
    }
  }
}

extern "C" void kernel_launch(void* const* d_in, const int* in_sizes, int n_in,
                              void* d_out, int out_size, void* d_ws, size_t ws_size,
                              hipStream_t stream) {
  const float* r_el  = (const float*)d_in[0];
  const float* cell  = (const float*)d_in[1];
  // d_in[2] = twist (unused by the reference)
  const float* W_e   = (const float*)d_in[3];
  const float* b_e   = (const float*)d_in[4];
  const float* W_pw  = (const float*)d_in[5];
  const float* b_pw  = (const float*)d_in[6];
  const float* W1    = (const float*)d_in[7];
  const float* b1    = (const float*)d_in[8];
  const float* W2    = (const float*)d_in[9];
  const float* b2    = (const float*)d_in[10];
  const float* ln_w  = (const float*)d_in[11];
  const float* ln_b  = (const float*)d_in[12];
  const float* W_up  = (const float*)d_in[13];
  const float* b_up  = (const float*)d_in[14];
  const float* W_dn  = (const float*)d_in[15];
  const float* b_dn  = (const float*)d_in[16];
  const float* det_w = (const float*)d_in[17];
  const float* Wj1   = (const float*)d_in[18];
  const float* bj1   = (const float*)d_in[19];
  const float* Wj2   = (const float*)d_in[20];
  const float* bj2   = (const float*)d_in[21];
  const float* Wj3   = (const float*)d_in[22];
  const float* bj3   = (const float*)d_in[23];
  const float* jsc   = (const float*)d_in[24];

  wf_kernel<<<N_WALK, 256, 0, stream>>>(
      r_el, cell, W_e, b_e, W_pw, b_pw, W1, b1, W2, b2, ln_w, ln_b,
      W_up, b_up, W_dn, b_dn, det_w, Wj1, bj1, Wj2, bj2, Wj3, bj3, jsc,
      (float*)d_out);
}

// Round 9
// 599.404 us; speedup vs baseline: 1.8348x; 1.1533x over previous
//
#include <hip/hip_runtime.h>

#define N_WALK 4096
#define N_EL   32
#define DIM    64
#define HPAD   68   // f32 row stride: 68%32=4 banks -> max 2-way conflict (free)
#define NLAY   3
#define KDET   16
#define NPAIR  496
#define TWO_PI_D 6.283185307179586476925286766559

using f64x4 = __attribute__((ext_vector_type(4))) double;

#define MFMA64(A, B, C) __builtin_amdgcn_mfma_f64_16x16x4f64((A), (B), (C), 0, 0, 0)

// fast f64 exp, rel err ~3e-13 for |x| <= 60
__device__ __forceinline__ double exp_d(double x) {
  const double LOG2E  = 1.4426950408889634074;
  const double LN2_HI = 6.93147180369123816490e-01;
  const double LN2_LO = 1.90821492927058770002e-10;
  const double nf = rint(x * LOG2E);
  double r = fma(-nf, LN2_HI, x);
  r = fma(-nf, LN2_LO, r);
  double p = 1.0/3628800.0;
  p = fma(p, r, 1.0/362880.0);
  p = fma(p, r, 1.0/40320.0);
  p = fma(p, r, 1.0/5040.0);
  p = fma(p, r, 1.0/720.0);
  p = fma(p, r, 1.0/120.0);
  p = fma(p, r, 1.0/24.0);
  p = fma(p, r, 1.0/6.0);
  p = fma(p, r, 0.5);
  p = fma(p, r, 1.0);
  p = fma(p, r, 1.0);
  const long long bits = ((long long)((int)nf + 1023)) << 52;
  return p * __longlong_as_double(bits);
}

// silu with Newton-recip division (rel err ~1e-14)
__device__ __forceinline__ double silu_d(double x) {
  const double d = 1.0 + exp_d(-x);
  const double q0 = (double)(1.0f / (float)d);
  double q = q0 * (2.0 - d * q0);
  q = q * (2.0 - d * q);
  return x * q;
}
__device__ __forceinline__ float silu_q(float x) { return x / (1.0f + __expf(-x)); }

__global__ __launch_bounds__(256) void wf_kernel(
    const float* __restrict__ r_el,
    const float* __restrict__ cell,
    const float* __restrict__ W_e,  const float* __restrict__ b_e,
    const float* __restrict__ W_pw, const float* __restrict__ b_pw,
    const float* __restrict__ W1,   const float* __restrict__ b1,
    const float* __restrict__ W2,   const float* __restrict__ b2,
    const float* __restrict__ ln_w, const float* __restrict__ ln_b,
    const float* __restrict__ W_up, const float* __restrict__ b_up,
    const float* __restrict__ W_dn, const float* __restrict__ b_dn,
    const float* __restrict__ det_w,
    const float* __restrict__ Wj1,  const float* __restrict__ bj1,
    const float* __restrict__ Wj2,  const float* __restrict__ bj2,
    const float* __restrict__ Wj3,  const float* __restrict__ bj3,
    const float* __restrict__ jscale,
    float* __restrict__ out)
{
  __shared__ float s_linv[9];
  __shared__ float s_cl[9];
  __shared__ float s_r[N_EL][3];
  __shared__ float s_pw[N_EL][6];
  __shared__ float s_h[N_EL][HPAD];
  // union buffer: stage-3 s_y [32][HPAD]=2176 floats; stage-5 phi [16][257]=4112 floats
  __shared__ float s_u[16*257];
  __shared__ float s_hm[DIM];
  __shared__ double s_hb[DIM];        // b1 + hm @ W1[64:128]  (f64, per layer)
  __shared__ double s_lu[2][KDET];
  __shared__ float  s_su[2][KDET];
  __shared__ float  s_red[4];
#define SY(e,d)   s_u[(e)*HPAD + (d)]
#define SORB(j,c) s_u[(j)*257 + (c)]

  const int t = threadIdx.x;
  const int w = blockIdx.x;
  const int wv = t >> 6;         // wave id 0..3
  const int l  = t & 63;
  const int lr = l & 15;         // row/col fragment index
  const int lq = l >> 4;         // k fragment index

  // ---- cell inverse: f64 compute, f32 round ----
  if (t == 0) {
    double m00=cell[0], m01=cell[1], m02=cell[2];
    double m10=cell[3], m11=cell[4], m12=cell[5];
    double m20=cell[6], m21=cell[7], m22=cell[8];
    double c00 = m11*m22 - m12*m21;
    double c10 = m12*m20 - m10*m22;
    double c20 = m10*m21 - m11*m20;
    double det = m00*c00 + m01*c10 + m02*c20;
    double id = 1.0/det;
    s_linv[0]=(float)(c00*id); s_linv[1]=(float)((m02*m21-m01*m22)*id); s_linv[2]=(float)((m01*m12-m02*m11)*id);
    s_linv[3]=(float)(c10*id); s_linv[4]=(float)((m00*m22-m02*m20)*id); s_linv[5]=(float)((m02*m10-m00*m12)*id);
    s_linv[6]=(float)(c20*id); s_linv[7]=(float)((m01*m20-m00*m21)*id); s_linv[8]=(float)((m00*m11-m01*m10)*id);
    #pragma unroll
    for (int i=0;i<9;i++) s_cl[i]=cell[i];
  }
  __syncthreads();

  // ---- stage 1: wrap + plane waves (f64 dots, f32 tensor boundaries) ----
  if (t < N_EL) {
    const float* rp = r_el + ((size_t)w * N_EL + t) * 3;
    const float rx = rp[0], ry = rp[1], rz = rp[2];
    float s0 = (float)((double)s_linv[0]*rx + (double)s_linv[1]*ry + (double)s_linv[2]*rz);
    float s1 = (float)((double)s_linv[3]*rx + (double)s_linv[4]*ry + (double)s_linv[5]*rz);
    float s2 = (float)((double)s_linv[6]*rx + (double)s_linv[7]*ry + (double)s_linv[8]*rz);
    s0 -= floorf(s0); s1 -= floorf(s1); s2 -= floorf(s2);
    const float wx = (float)((double)s0*s_cl[0] + (double)s1*s_cl[3] + (double)s2*s_cl[6]);
    const float wy = (float)((double)s0*s_cl[1] + (double)s1*s_cl[4] + (double)s2*s_cl[7]);
    const float wz = (float)((double)s0*s_cl[2] + (double)s1*s_cl[5] + (double)s2*s_cl[8]);
    s_r[t][0]=wx; s_r[t][1]=wy; s_r[t][2]=wz;
    const float u0 = (float)((double)s_linv[0]*wx + (double)s_linv[1]*wy + (double)s_linv[2]*wz);
    const float u1 = (float)((double)s_linv[3]*wx + (double)s_linv[4]*wy + (double)s_linv[5]*wz);
    const float u2 = (float)((double)s_linv[6]*wx + (double)s_linv[7]*wy + (double)s_linv[8]*wz);
    double sn, cs;
    sincos(TWO_PI_D*(double)u0, &sn, &cs); s_pw[t][0]=(float)sn; s_pw[t][3]=(float)cs;
    sincos(TWO_PI_D*(double)u1, &sn, &cs); s_pw[t][1]=(float)sn; s_pw[t][4]=(float)cs;
    sincos(TWO_PI_D*(double)u2, &sn, &cs); s_pw[t][2]=(float)sn; s_pw[t][5]=(float)cs;
  }
  __syncthreads();

  // ---- stage 2: h0 (f64 acc -> f32 store) ----
  {
    const int e = t >> 3, db = (t & 7) * 8;
    const double rx=s_r[e][0], ry=s_r[e][1], rz=s_r[e][2];
    const double p0=s_pw[e][0],p1=s_pw[e][1],p2=s_pw[e][2];
    const double p3=s_pw[e][3],p4=s_pw[e][4],p5=s_pw[e][5];
    #pragma unroll
    for (int u=0;u<8;u++) {
      const int d = db+u;
      double acc = (double)b_e[d] + (double)b_pw[d];
      acc = fma(rx, (double)W_e[0*DIM+d], acc);
      acc = fma(ry, (double)W_e[1*DIM+d], acc);
      acc = fma(rz, (double)W_e[2*DIM+d], acc);
      acc = fma(p0, (double)W_pw[0*DIM+d], acc);
      acc = fma(p1, (double)W_pw[1*DIM+d], acc);
      acc = fma(p2, (double)W_pw[2*DIM+d], acc);
      acc = fma(p3, (double)W_pw[3*DIM+d], acc);
      acc = fma(p4, (double)W_pw[4*DIM+d], acc);
      acc = fma(p5, (double)W_pw[5*DIM+d], acc);
      s_h[e][d] = (float)acc;
    }
  }
  __syncthreads();

  // ---- stage 3: interaction layers via f64 MFMA ----
  for (int L = 0; L < NLAY; ++L) {
    const float* __restrict__ w1p = W1 + (size_t)L*192*DIM;
    const float* __restrict__ w2p = W2 + (size_t)L*DIM*DIM;

    // hm (f32 tensor) + hb = b1 + hm @ W1[64:128] (f64 rank-1 hoist).
    // Single wave (t<64): lockstep write->read of s_hm is wave-coherent.
    if (t < DIM) {
      double s = 0.0;
      #pragma unroll 8
      for (int e=0;e<N_EL;e++) s += (double)s_h[e][t];
      const float hmf = (float)(s * (1.0/N_EL));
      s_hm[t] = hmf;
      double hb = (double)b1[L*DIM + t];
      #pragma unroll 8
      for (int km=0;km<DIM;km++)
        hb = fma((double)s_hm[km], (double)w1p[(64+km)*DIM + t], hb);
      s_hb[t] = hb;
    }
    __syncthreads();

    const int m  = wv & 1;
    const int nb = (wv >> 1) * 2;
    const int ea = m*16 + lr;        // A-fragment row (electron)
    const int c0 = nb*16 + lr;       // D/B column of tile 0 (tile 1 = c0+16)
    const int er = m*16 + lq*4;      // D row base

    // --- y = silu(h@W1a + (h*hm)@W1c + hb) ---
    {
      f64x4 a0 = {0.0,0.0,0.0,0.0}, a1 = {0.0,0.0,0.0,0.0};
      #pragma unroll
      for (int kk=0;kk<16;kk++) {              // K seg 0: x = h
        const int km = kk*4 + lq;
        const double af = (double)s_h[ea][km];
        const double q0 = (double)w1p[km*DIM + c0];
        const double q1 = (double)w1p[km*DIM + c0 + 16];
        a0 = MFMA64(af, q0, a0);
        a1 = MFMA64(af, q1, a1);
      }
      #pragma unroll
      for (int kk=0;kk<16;kk++) {              // K seg 2: x = h*hm (f32 product)
        const int km = kk*4 + lq;
        const double af = (double)(s_h[ea][km] * s_hm[km]);
        const double q0 = (double)w1p[(128+km)*DIM + c0];
        const double q1 = (double)w1p[(128+km)*DIM + c0 + 16];
        a0 = MFMA64(af, q0, a0);
        a1 = MFMA64(af, q1, a1);
      }
      #pragma unroll
      for (int v=0;v<4;v++) {
        const float p0 = (float)(a0[v] + s_hb[c0]);        // np pre-act (f64 reorder)
        const float p1 = (float)(a1[v] + s_hb[c0 + 16]);
        SY(er+v, c0)      = (float)silu_d((double)p0);
        SY(er+v, c0 + 16) = (float)silu_d((double)p1);
      }
    }
    __syncthreads();

    // --- delta = y @ W2 + b2 ; v = h + delta written DIRECTLY to s_h
    //     (own tile read+write only; s_y untouched -> no mid barrier) ---
    {
      f64x4 a0 = {0.0,0.0,0.0,0.0}, a1 = {0.0,0.0,0.0,0.0};
      #pragma unroll
      for (int kk=0;kk<16;kk++) {
        const int km = kk*4 + lq;
        const double af = (double)SY(ea, km);
        const double q0 = (double)w2p[km*DIM + c0];
        const double q1 = (double)w2p[km*DIM + c0 + 16];
        a0 = MFMA64(af, q0, a0);
        a1 = MFMA64(af, q1, a1);
      }
      #pragma unroll
      for (int v=0;v<4;v++) {
        const float d0 = (float)(a0[v] + (double)b2[L*DIM + c0]);      // np delta
        const float d1 = (float)(a1[v] + (double)b2[L*DIM + c0 + 16]);
        s_h[er+v][c0]      = s_h[er+v][c0]      + d0;                  // np h+delta
        s_h[er+v][c0 + 16] = s_h[er+v][c0 + 16] + d1;
      }
    }
    __syncthreads();

    // --- LayerNorm: stats f64 (Newton rstd), reads v from s_h, writes s_h ---
    {
      const int e = t >> 3, db = (t & 7) * 8;
      float v[8];
      double ps=0.0, pss=0.0;
      #pragma unroll
      for (int u=0;u<8;u++) {
        v[u] = s_h[e][db+u];
        ps += (double)v[u]; pss += (double)v[u]*(double)v[u];
      }
      #pragma unroll
      for (int off=4; off>=1; off>>=1) {
        ps  += __shfl_xor(ps,  off, 8);
        pss += __shfl_xor(pss, off, 8);
      }
      const double mu = ps * (1.0/DIM);
      double var = pss * (1.0/DIM) - mu*mu;
      var = fmax(var, 0.0);
      const double s = var + 1e-5;
      double rstd = (double)rsqrtf((float)s);
      rstd = rstd * (1.5 - 0.5*s*rstd*rstd);
      rstd = rstd * (1.5 - 0.5*s*rstd*rstd);
      #pragma unroll
      for (int u=0;u<8;u++) {
        const int d = db+u;
        s_h[e][d] = (float)(((double)v[u]-mu)*rstd*(double)ln_w[L*DIM+d] + (double)ln_b[L*DIM+d]);
      }
    }
    __syncthreads();
  }

  // ---- stage 4: Jastrow (f32, fast exp — additive path, noise ~1e-5) ----
  float jpart = 0.f;
  for (int p = t; p < NPAIR; p += 256) {
    int i = 0, rem = p;
    while (rem >= (N_EL-1) - i) { rem -= (N_EL-1) - i; ++i; }
    const int j = i + 1 + rem;
    const float dx = s_r[i][0]-s_r[j][0];
    const float dy = s_r[i][1]-s_r[j][1];
    const float dz = s_r[i][2]-s_r[j][2];
    float q0 = (float)((double)s_linv[0]*dx + (double)s_linv[1]*dy + (double)s_linv[2]*dz);
    float q1 = (float)((double)s_linv[3]*dx + (double)s_linv[4]*dy + (double)s_linv[5]*dz);
    float q2 = (float)((double)s_linv[6]*dx + (double)s_linv[7]*dy + (double)s_linv[8]*dz);
    q0 -= rintf(q0); q1 -= rintf(q1); q2 -= rintf(q2);
    const float vx = (float)((double)q0*s_cl[0] + (double)q1*s_cl[3] + (double)q2*s_cl[6]);
    const float vy = (float)((double)q0*s_cl[1] + (double)q1*s_cl[4] + (double)q2*s_cl[7]);
    const float vz = (float)((double)q0*s_cl[2] + (double)q1*s_cl[5] + (double)q2*s_cl[8]);
    const float rij = sqrtf(vx*vx + vy*vy + vz*vz);
    float h1[32];
    #pragma unroll
    for (int mm=0;mm<32;mm++) h1[mm] = silu_q(fmaf(rij, Wj1[mm], bj1[mm]));
    float o = bj3[0];
    for (int n=0;n<32;n++) {
      float a2 = bj2[n];
      #pragma unroll
      for (int mm=0;mm<32;mm++) a2 = fmaf(h1[mm], Wj2[mm*32+n], a2);
      o = fmaf(silu_q(a2), Wj3[n], o);
    }
    jpart += o;
  }
  #pragma unroll
  for (int off=32; off>=1; off>>=1) jpart += __shfl_xor(jpart, off, 64);
  if ((t & 63) == 0) s_red[t >> 6] = jpart;
  __syncthreads();

  // ---- stage 5+6: orbitals via f64 MFMA into padded LDS (per spin), then LU ----
  {
    const int g4 = wv * 4;
    const int g  = t >> 4;
    const int r  = t & 15;
    #pragma unroll 1
    for (int sp=0; sp<2; ++sp) {
      const float* __restrict__ Wo = sp ? W_dn : W_up;
      const float* __restrict__ bo = sp ? b_dn : b_up;
      const int arow = sp*16 + lr;     // A row = lr, A k = lq
      #pragma unroll 1
      for (int gi=0; gi<4; ++gi) {
        const int cb = (g4 + gi)*16 + lr;      // B/D column
        f64x4 ac = {0.0,0.0,0.0,0.0};
        #pragma unroll
        for (int kk=0;kk<16;kk++) {
          const int km = kk*4 + lq;
          const double av = (double)s_h[arow][km];
          const double bv = (double)Wo[(size_t)km*256 + cb];
          ac = MFMA64(av, bv, ac);
        }
        const int row = lq*4;
        #pragma unroll
        for (int v=0;v<4;v++)
          SORB(row+v, cb) = (float)(ac[v] + (double)bo[cb]);   // f32 round = np orb
      }
      __syncthreads();

      double a[16];
      #pragma unroll
      for (int j=0;j<16;j++) a[j] = (double)SORB(j, t);

      // --- LU, partial pivoting, merged swap+elim.
      //     Bitwise-identical to the R4/R8 LU: per step, post-swap value of
      //     lane r is shfl(a[j], src) with src=(r==k)?p:((r==p)?k:r); row-k
      //     broadcast (post-swap) is shfl(a[j], p). Same fma/div operands. ---
      double prod = 1.0;
      int par = 0;
      #pragma unroll
      for (int k=0;k<16;k++) {
        float bv = (r >= k) ? (float)fabs(a[k]) : -1.0f;
        int bi = r;
        #pragma unroll
        for (int off=8; off>=1; off>>=1) {
          const float ov = __shfl_xor(bv, off, 16);
          const int   oi = __shfl_xor(bi, off, 16);
          if (ov > bv || (ov == bv && oi < bi)) { bv = ov; bi = oi; }
        }
        const int p = bi;
        par += (p != k) ? 1 : 0;
        const int src = (r == k) ? p : ((r == p) ? k : r);
        const double piv   = __shfl(a[k], p, 16);    // post-swap pivot (uniform)
        const double newak = __shfl(a[k], src, 16);  // post-swap own a[k]
        prod *= piv;
        const double f = (r > k && piv != 0.0) ? newak/piv : 0.0;
        a[k] = newak;
        #pragma unroll
        for (int j=k+1;j<16;j++) {
          const double sw = __shfl(a[j], src, 16);   // post-swap own value
          const double kj = __shfl(a[j], p, 16);     // post-swap row-k value
          a[j] = fma(-f, kj, sw);
        }
      }
      if (r == 0) {
        s_lu[sp][g] = log(fabs(prod));
        const int neg = (prod < 0.0) ? 1 : 0;
        s_su[sp][g] = ((par + neg) & 1) ? -1.f : 1.f;
      }
      __syncthreads();
    }
  }

  // ---- stage 7: signed logsumexp combine (f64, 16-thread parallel) ----
  if (t < 16) {
    const int k = t;
    const double wwk = (double)det_w[k];
    double mw = wwk;
    #pragma unroll
    for (int off=8; off>=1; off>>=1) mw = fmax(mw, __shfl_xor(mw, off, 16));
    const double ew = exp_d(wwk - mw);
    double sum = ew;
    #pragma unroll
    for (int off=8; off>=1; off>>=1) sum += __shfl_xor(sum, off, 16);
    const double lg = s_lu[0][k] + s_lu[1][k] + log(ew/sum + 1e-10);
    const double sg = (double)(s_su[0][k] * s_su[1][k]);
    double m = lg;
    #pragma unroll
    for (int off=8; off>=1; off>>=1) m = fmax(m, __shfl_xor(m, off, 16));
    double ssum = sg * exp_d(lg - m);
    #pragma unroll
    for (int off=8; off>=1; off>>=1) ssum += __shfl_xor(ssum, off, 16);
    if (t == 0) {
      const double jas = (double)jscale[0] * (double)(s_red[0]+s_red[1]+s_red[2]+s_red[3]);
      out[w] = (float)(jas + m + log(fabs(ssum) + 1e-30));
      out[N_WALK + w] = (ssum > 0.0) ? 1.f : ((ssum < 0.0) ? -1.f : 0.f);
    }
  }
}

extern "C" void kernel_launch(void* const* d_in, const int* in_sizes, int n_in,
                              void* d_out, int out_size, void* d_ws, size_t ws_size,
                              hipStream_t stream) {
  const float* r_el  = (const float*)d_in[0];
  const float* cell  = (const float*)d_in[1];
  // d_in[2] = twist (unused by the reference)
  const float* W_e   = (const float*)d_in[3];
  const float* b_e   = (const float*)d_in[4];
  const float* W_pw  = (const float*)d_in[5];
  const float* b_pw  = (const float*)d_in[6];
  const float* W1    = (const float*)d_in[7];
  const float* b1    = (const float*)d_in[8];
  const float* W2    = (const float*)d_in[9];
  const float* b2    = (const float*)d_in[10];
  const float* ln_w  = (const float*)d_in[11];
  const float* ln_b  = (const float*)d_in[12];
  const float* W_up  = (const float*)d_in[13];
  const float* b_up  = (const float*)d_in[14];
  const float* W_dn  = (const float*)d_in[15];
  const float* b_dn  = (const float*)d_in[16];
  const float* det_w = (const float*)d_in[17];
  const float* Wj1   = (const float*)d_in[18];
  const float* bj1   = (const float*)d_in[19];
  const float* Wj2   = (const float*)d_in[20];
  const float* bj2   = (const float*)d_in[21];
  const float* Wj3   = (const float*)d_in[22];
  const float* bj3   = (const float*)d_in[23];
  const float* jsc   = (const float*)d_in[24];

  wf_kernel<<<N_WALK, 256, 0, stream>>>(
      r_el, cell, W_e, b_e, W_pw, b_pw, W1, b1, W2, b2, ln_w, ln_b,
      W_up, b_up, W_dn, b_dn, det_w, Wj1, bj1, Wj2, bj2, Wj3, bj3, jsc,
      (float*)d_out);
}